// Round 2
// baseline (2009.592 us; speedup 1.0000x reference)
//
#include <hip/hip_runtime.h>
#include <hip/hip_bf16.h>

#define S_SPK 2
#define BATCH 16
#define TMAX 300
#define CLASSES 3000
#define NUM_STATES 400
#define NUM_ARCS 1200
#define DEN_STATES 3000
#define DEN_ARCS 60000

#define BLK 768               // threads per forward block (12 waves)
#define NWAVE 12
#define KCH 4                 // den chunks per sequence
#define CHST 750              // 3000 / 4
#define NSEQ 32               // S_SPK * BATCH
#define NUM_CAP_G 2400        // per graph: 1200 + 3*400
#define NGRAPH 32             // (p,b) graphs

// ---------------- workspace layout (bytes) ----------------
#define WS_DEN_ARCS   0              // 72000*8   = 576000
#define WS_NUM_ARCS   576000         // 32*2400*8 = 614400 -> 1190400
#define WS_DEN_CNT    1190400        // 3000*4    -> 1202400
#define WS_DEN_R      1202400        // 3001*4    -> 1214416 (pad)
#define WS_DEN_CUR    1214416        // 3000*4    -> 1226416
#define WS_NUM_CNT    1226416        // 32*400*4  -> 1277616
#define WS_NUM_R      1277616        // 32*401*4  -> 1328944
#define WS_NUM_CUR    1328944        // 32*400*4  -> 1380144
#define WS_GALPHA     1380144        // 32*2*3000*4 = 768000 -> 2148144
#define WS_FLAGS      2148144        // 32*4*16*4 = 8192 -> 2156336 (64B/flag)
#define WS_BINS       2156336        // 64*4 -> 2156592  (count histogram)
#define WS_DEN_Z      2156592        // 32 floats -> 2156720
#define WS_NUM_Z      2156720        // 64 floats -> 2156976
#define WS_BINCUR     2156976        // 64*4 -> 2157232
#define WS_PI         2157232        // 3000*4 -> 2169232 (state -> position)
#define WS_INV        2169232        // 3000*4 -> 2181232 (position -> state)
#define WS_CNTP       2181232        // 3000*4 -> 2193232 (cnt by position)
#define WS_ZERO_INTS  (2156592 / 4)  // zero everything below den_z

// ---------------------------------------------------------------------------
__global__ void zero_ws(int* __restrict__ p, int n) {
    int i = blockIdx.x * blockDim.x + threadIdx.x;
    for (; i < n; i += gridDim.x * blockDim.x) p[i] = 0;
}

__global__ void hist_den(const int* __restrict__ dst, int* __restrict__ cnt) {
    int i = blockIdx.x * blockDim.x + threadIdx.x;
    if (i < DEN_ARCS) atomicAdd(&cnt[dst[i]], 1);
}

__global__ void hist_num(const int* __restrict__ dst, int* __restrict__ cnt) {
    int i = blockIdx.x * blockDim.x + threadIdx.x;
    if (i < NGRAPH * NUM_ARCS) {
        int g = i / NUM_ARCS;
        atomicAdd(&cnt[g * NUM_STATES + dst[i]], 1);
    }
}

// ---- load-balancing permutation: counting-sort states by arc count (desc),
// ---- deal round-robin across the 4 chunks so each wave holds like-count
// ---- states (wave pays its max lane; sorting makes max ~= mean).
__global__ void bin_hist(const int* __restrict__ cnt, int* __restrict__ bins) {
    int s = blockIdx.x * blockDim.x + threadIdx.x;
    if (s < DEN_STATES) {
        int c = cnt[s]; if (c > 63) c = 63;
        atomicAdd(&bins[c], 1);
    }
}

// 1 block, 64 threads: bincur[b] = #states with count > b (descending ranks)
__global__ void bin_scan(const int* __restrict__ bins, int* __restrict__ bincur) {
    __shared__ int sb[64];
    int tid = threadIdx.x;
    sb[tid] = bins[tid];
    __syncthreads();
    int sum = 0;
    for (int b = 63; b > tid; --b) sum += sb[b];
    bincur[tid] = sum;
}

__global__ void rank_scatter(const int* __restrict__ cnt, int* __restrict__ bincur,
                             int* __restrict__ pi, int* __restrict__ inv) {
    int s = blockIdx.x * blockDim.x + threadIdx.x;
    if (s < DEN_STATES) {
        int c = cnt[s]; if (c > 63) c = 63;
        int rank = atomicAdd(&bincur[c], 1);          // rank 0 = heaviest
        int pos = (rank & (KCH - 1)) * CHST + (rank >> 2);  // deal across chunks
        pi[s] = pos;
        inv[pos] = s;
    }
}

__global__ void permute_cnt(const int* __restrict__ cnt, const int* __restrict__ inv,
                            int* __restrict__ cntp) {
    int p = blockIdx.x * blockDim.x + threadIdx.x;
    if (p < DEN_STATES) cntp[p] = cnt[inv[p]];
}

// one block, 1024 threads: per-POSITION x4-padded prefix for den CSR
__global__ void scan_den(const int* __restrict__ cnt, int* __restrict__ R) {
    __shared__ int sc[1024];
    int tid = threadIdx.x;
    int c0 = 0, c1 = 0, c2 = 0, p0 = 0, p1 = 0, p2 = 0, pg = 0;
    if (tid < 1000) {
        c0 = cnt[3 * tid]; c1 = cnt[3 * tid + 1]; c2 = cnt[3 * tid + 2];
        p0 = (c0 + 3) & ~3; p1 = (c1 + 3) & ~3; p2 = (c2 + 3) & ~3;
        pg = p0 + p1 + p2;
    }
    sc[tid] = pg; __syncthreads();
    for (int o = 1; o < 1024; o <<= 1) {
        int v = (tid >= o) ? sc[tid - o] : 0;
        __syncthreads(); sc[tid] += v; __syncthreads();
    }
    int ex = sc[tid] - pg;
    if (tid < 1000) {
        R[3 * tid] = ex; R[3 * tid + 1] = ex + p0; R[3 * tid + 2] = ex + p0 + p1;
    }
    if (tid == 1000) R[3000] = ex;  // total
}

// 32 blocks x 512: per-graph padded per-state prefix (num)
__global__ void scan_num(const int* __restrict__ cnt, int* __restrict__ R) {
    __shared__ int sc[512];
    int g = blockIdx.x, tid = threadIdx.x;
    int c = 0, pg = 0;
    if (tid < NUM_STATES) { c = cnt[g * NUM_STATES + tid]; pg = (c + 3) & ~3; }
    sc[tid] = pg; __syncthreads();
    for (int o = 1; o < 512; o <<= 1) {
        int v = (tid >= o) ? sc[tid - o] : 0;
        __syncthreads(); sc[tid] += v; __syncthreads();
    }
    int ex = sc[tid] - pg;
    if (tid <= NUM_STATES) R[g * (NUM_STATES + 1) + tid] = ex;
}

__global__ void scat_den(const int* __restrict__ src, const int* __restrict__ dst,
                         const int* __restrict__ lab, const float* __restrict__ w,
                         const int* __restrict__ R, int* __restrict__ cur,
                         const int* __restrict__ pi, int2* __restrict__ out) {
    int i = blockIdx.x * blockDim.x + threadIdx.x;
    if (i >= DEN_ARCS) return;
    int dpos = pi[dst[i]];
    int spos = pi[src[i]];
    int pos = R[dpos] + atomicAdd(&cur[dpos], 1);
    out[pos] = make_int2(spos | (lab[i] << 16), __float_as_int(__expf(w[i])));
}

__global__ void scat_num(const int* __restrict__ src, const int* __restrict__ dst,
                         const int* __restrict__ lab, const float* __restrict__ w,
                         const int* __restrict__ R, int* __restrict__ cur,
                         int2* __restrict__ out) {
    int i = blockIdx.x * blockDim.x + threadIdx.x;
    if (i >= NGRAPH * NUM_ARCS) return;
    int g = i / NUM_ARCS;
    int d = dst[i];
    int pos = R[g * (NUM_STATES + 1) + d] + atomicAdd(&cur[g * NUM_STATES + d], 1);
    out[g * NUM_CAP_G + pos] =
        make_int2(src[i] | (lab[i] << 16), __float_as_int(__expf(w[i])));
}

// ---------------------------------------------------------------------------
// num forward: single 768-thread block, prob domain, 1 state/thread
// ---------------------------------------------------------------------------
__device__ __forceinline__ void num_fwd(
    const int* __restrict__ R, const int2* __restrict__ arcs,
    const float* __restrict__ start, const float* __restrict__ fin,
    const float* __restrict__ est, int L, float* __restrict__ out,
    float* A0, float* A1, float* p, float* red)
{
    const int tid = threadIdx.x, lane = tid & 63, wid = tid >> 6;

    if (tid < NUM_STATES) A0[tid] = __expf(start[tid]);

    int rs = 0, re = 0;
    if (tid < NUM_STATES) { rs = R[tid]; re = R[tid + 1]; }

    float l0 = est[tid], l1 = est[tid + 768], l2 = est[tid + 1536];
    float l3 = (tid < 696) ? est[tid + 2304] : 0.f;

    float c = 1.f, OFF = 0.f, pend = 0.f;
    const int4* arcs4 = (const int4*)arcs;

    for (int t = 0; t < L; ++t) {
        OFF += pend;
        p[tid] = __expf(l0) * c;        p[tid + 768] = __expf(l1) * c;
        p[tid + 1536] = __expf(l2) * c;
        if (tid < 696) p[tid + 2304] = __expf(l3) * c;
        {
            const float* nr = est + (size_t)((t + 1 < L) ? (t + 1) : t) * CLASSES;
            l0 = nr[tid]; l1 = nr[tid + 768]; l2 = nr[tid + 1536];
            if (tid < 696) l3 = nr[tid + 2304];
        }
        __syncthreads();   // p ready (also protects red[] from prev iter reads)

        const float* Ac = (t & 1) ? A1 : A0;
        float*       An = (t & 1) ? A0 : A1;
        float a0 = 0.f;
        for (int r = rs; r < re; r += 4) {
            int4 q0 = arcs4[(r >> 1)];
            int4 q1 = arcs4[(r >> 1) + 1];
            a0 += Ac[q0.x & 0xffff] * p[((unsigned)q0.x) >> 16] * __int_as_float(q0.y);
            a0 += Ac[q0.z & 0xffff] * p[((unsigned)q0.z) >> 16] * __int_as_float(q0.w);
            a0 += Ac[q1.x & 0xffff] * p[((unsigned)q1.x) >> 16] * __int_as_float(q1.y);
            a0 += Ac[q1.z & 0xffff] * p[((unsigned)q1.z) >> 16] * __int_as_float(q1.w);
        }
        float mymax = 0.f;
        if (tid < NUM_STATES) { An[tid] = a0; mymax = a0; }
        #pragma unroll
        for (int o = 32; o > 0; o >>= 1) mymax = fmaxf(mymax, __shfl_down(mymax, o, 64));
        if (lane == 0) red[wid] = mymax;
        __syncthreads();
        float M = red[0];
        #pragma unroll
        for (int k = 1; k < NWAVE; ++k) M = fmaxf(M, red[k]);
        M = fmaxf(M, 1e-37f);
        c = 1.0f / M;
        pend = __logf(M);
    }

    const float* Af = (L & 1) ? A1 : A0;
    float fs = 0.f;
    if (tid < NUM_STATES) fs = Af[tid] * __expf(fin[tid]);
    __syncthreads();   // red[] settled
    #pragma unroll
    for (int o = 32; o > 0; o >>= 1) fs += __shfl_down(fs, o, 64);
    if (lane == 0) red[wid] = fs;
    __syncthreads();
    if (tid == 0) {
        float s = 0.f;
        #pragma unroll
        for (int k = 0; k < NWAVE; ++k) s += red[k];
        out[0] = OFF + __logf(s);
    }
}

// ---------------------------------------------------------------------------
// Fused forward: blocks [0,128) = den chunk*32+seq; [128,192) = num.
// Den: k=4 chunks exchange alpha per step via LLC.
// States are PERMUTED (counting-sorted by arc count, dealt across chunks) so
// each wave's 64 states have similar arc counts -> wave-max ~= wave-mean.
// Sync: per-chunk 64B release flags; RELAXED polls (no buffer_inv; agent
// atomics bypass L1/L2 and read the LLC directly). Producer ordering via
// __syncthreads() vmcnt drain + RELEASE flag store.
// ---------------------------------------------------------------------------
__global__ __launch_bounds__(BLK) void forward_kernel(
    const float* __restrict__ est, const int* __restrict__ seqlen,
    const int2* __restrict__ den_arcs, const int* __restrict__ den_R,
    const float* __restrict__ den_start, const float* __restrict__ den_final,
    const int* __restrict__ den_inv,
    const int2* __restrict__ num_arcs, const int* __restrict__ num_R,
    const float* __restrict__ num_start, const float* __restrict__ num_final,
    float* __restrict__ galpha, unsigned* __restrict__ flags,
    float* __restrict__ den_z, float* __restrict__ num_z)
{
    __shared__ float S1[DEN_STATES];   // den: alpha_prev | num: A0 (+A1 at 1536)
    __shared__ float S2[CLASSES];      // p
    __shared__ float red[16];

    const int blk = blockIdx.x;
    const int tid = threadIdx.x, lane = tid & 63, wid = tid >> 6;

    if (blk < KCH * NSEQ) {
        const int seq = blk & 31;        // chunks of a seq share XCD residue
        const int chunk = blk >> 5;
        const int b = seq & 15;
        const int L = seqlen[b];
        const float* est_base = est + (size_t)seq * TMAX * CLASSES;
        const int base = chunk * CHST;
        unsigned* myflag = &flags[(seq * KCH + chunk) * 16];
        const unsigned* flbase = &flags[seq * KCH * 16];

        int rs = 0, re = 0;
        if (tid < CHST) { rs = den_R[base + tid]; re = den_R[base + tid + 1]; }

        float l0 = est_base[tid], l1 = est_base[tid + 768], l2 = est_base[tid + 1536];
        float l3 = (tid < 696) ? est_base[tid + 2304] : 0.f;

        float OFF = 0.f;
        const int4* arcs4 = (const int4*)den_arcs;

        for (int t = 0; t < L; ++t) {
            // stage p_raw = exp(llh); prefetch next row (overlaps poll)
            S2[tid] = __expf(l0); S2[tid + 768] = __expf(l1); S2[tid + 1536] = __expf(l2);
            if (tid < 696) S2[tid + 2304] = __expf(l3);
            {
                const float* nr = est_base + (size_t)((t + 1 < L) ? (t + 1) : t) * CLASSES;
                l0 = nr[tid]; l1 = nr[tid + 768]; l2 = nr[tid + 1536];
                if (tid < 696) l3 = nr[tid + 2304];
            }

            float cM;
            if (t == 0) {
                // positions are permuted: start value for position p is
                // den_start[inv[p]]
                S1[tid] = __expf(den_start[den_inv[tid]]);
                S1[tid + 768] = __expf(den_start[den_inv[tid + 768]]);
                S1[tid + 1536] = __expf(den_start[den_inv[tid + 1536]]);
                if (tid < 696) S1[tid + 2304] = __expf(den_start[den_inv[tid + 2304]]);
                cM = 1.0f;
                __syncthreads();                               // B (S1,S2 ready)
            } else {
                // wave-0-only poll: lanes 0..3 spin on the 4 flags (RELAXED)
                if (tid < KCH) {
                    const unsigned* fp = &flbase[tid * 16];
                    const unsigned tgt = (unsigned)t;
                    while (__hip_atomic_load(fp, __ATOMIC_RELAXED,
                                             __HIP_MEMORY_SCOPE_AGENT) < tgt)
                        __builtin_amdgcn_s_sleep(1);
                }
                asm volatile("" ::: "memory");                 // compiler fence only
                __syncthreads();                               // A (flags passed, S2 ready)
                const float* gaP = galpha + ((size_t)seq * 2 + ((t - 1) & 1)) * DEN_STATES;
                float x0 = __hip_atomic_load(&gaP[tid], __ATOMIC_RELAXED, __HIP_MEMORY_SCOPE_AGENT);
                float x1 = __hip_atomic_load(&gaP[tid + 768], __ATOMIC_RELAXED, __HIP_MEMORY_SCOPE_AGENT);
                float x2 = __hip_atomic_load(&gaP[tid + 1536], __ATOMIC_RELAXED, __HIP_MEMORY_SCOPE_AGENT);
                float x3 = (tid < 696)
                    ? __hip_atomic_load(&gaP[tid + 2304], __ATOMIC_RELAXED, __HIP_MEMORY_SCOPE_AGENT)
                    : 0.f;
                S1[tid] = x0; S1[tid + 768] = x1; S1[tid + 1536] = x2;
                if (tid < 696) S1[tid + 2304] = x3;
                // consumer-side global max (identical in every chunk)
                float mymax = fmaxf(fmaxf(x0, x1), fmaxf(x2, x3));
                #pragma unroll
                for (int o = 32; o > 0; o >>= 1)
                    mymax = fmaxf(mymax, __shfl_down(mymax, o, 64));
                if (lane == 0) red[wid] = mymax;
                __syncthreads();                               // B (S1, red ready)
                float M = red[0];
                #pragma unroll
                for (int k = 1; k < NWAVE; ++k) M = fmaxf(M, red[k]);
                M = fmaxf(M, 1e-37f);
                cM = 1.0f / M;
                OFF += __logf(M);
            }

            float acc = 0.f;
            for (int r = rs; r < re; r += 4) {
                int4 q0 = arcs4[(r >> 1)];
                int4 q1 = arcs4[(r >> 1) + 1];
                acc += S1[q0.x & 0xffff] * S2[((unsigned)q0.x) >> 16] * __int_as_float(q0.y);
                acc += S1[q0.z & 0xffff] * S2[((unsigned)q0.z) >> 16] * __int_as_float(q0.w);
                acc += S1[q1.x & 0xffff] * S2[((unsigned)q1.x) >> 16] * __int_as_float(q1.y);
                acc += S1[q1.z & 0xffff] * S2[((unsigned)q1.z) >> 16] * __int_as_float(q1.w);
            }
            float val = acc * cM;

            float* gaW = galpha + ((size_t)seq * 2 + (t & 1)) * DEN_STATES;
            if (tid < CHST)
                __hip_atomic_store(&gaW[base + tid], val, __ATOMIC_RELAXED,
                                   __HIP_MEMORY_SCOPE_AGENT);   // contiguous/coalesced
            __syncthreads();        // C: stores drained (vmcnt(0) before s_barrier)
            if (tid == 0)
                __hip_atomic_store(myflag, (unsigned)(t + 1), __ATOMIC_RELEASE,
                                   __HIP_MEMORY_SCOPE_AGENT);
        }

        // epilogue: chunk 0 computes logZ from final buffer
        if (chunk == 0) {
            if (tid < KCH) {
                const unsigned* fp = &flbase[tid * 16];
                const unsigned tgt = (unsigned)L;
                while (__hip_atomic_load(fp, __ATOMIC_RELAXED,
                                         __HIP_MEMORY_SCOPE_AGENT) < tgt)
                    __builtin_amdgcn_s_sleep(1);
            }
            asm volatile("" ::: "memory");                     // compiler fence only
            __syncthreads();
            const float* gaF = galpha + ((size_t)seq * 2 + ((L - 1) & 1)) * DEN_STATES;
            float fs = 0.f;
            fs += __hip_atomic_load(&gaF[tid], __ATOMIC_RELAXED, __HIP_MEMORY_SCOPE_AGENT)
                  * __expf(den_final[den_inv[tid]]);
            fs += __hip_atomic_load(&gaF[tid + 768], __ATOMIC_RELAXED, __HIP_MEMORY_SCOPE_AGENT)
                  * __expf(den_final[den_inv[tid + 768]]);
            fs += __hip_atomic_load(&gaF[tid + 1536], __ATOMIC_RELAXED, __HIP_MEMORY_SCOPE_AGENT)
                  * __expf(den_final[den_inv[tid + 1536]]);
            if (tid < 696)
                fs += __hip_atomic_load(&gaF[tid + 2304], __ATOMIC_RELAXED, __HIP_MEMORY_SCOPE_AGENT)
                      * __expf(den_final[den_inv[tid + 2304]]);
            #pragma unroll
            for (int o = 32; o > 0; o >>= 1) fs += __shfl_down(fs, o, 64);
            if (lane == 0) red[wid] = fs;
            __syncthreads();
            if (tid == 0) {
                float s = 0.f;
                #pragma unroll
                for (int k = 0; k < NWAVE; ++k) s += red[k];
                den_z[seq] = OFF + __logf(s);
            }
        }
    } else {
        const int q = blk - KCH * NSEQ;
        const int b = q & 15;
        const int sp = q >> 4;
        const int s = sp >> 1, pp = sp & 1;
        const int L = seqlen[b];
        const int g = pp * BATCH + b;
        num_fwd(num_R + (size_t)g * (NUM_STATES + 1),
                num_arcs + (size_t)g * NUM_CAP_G,
                num_start + (size_t)g * NUM_STATES,
                num_final + (size_t)g * NUM_STATES,
                est + (size_t)(s * BATCH + b) * TMAX * CLASSES, L, &num_z[q],
                S1, S1 + 1536, S2, red);
    }
}

// ---------------------------------------------------------------------------
__global__ void loss_kernel(const float* __restrict__ den_z,
                            const float* __restrict__ num_z,
                            float* __restrict__ out)
{
    int tid = threadIdx.x;
    float l = 0.f;
    if (tid < BATCH) {
        int b = tid;
        float z00 = num_z[(0 * 2 + 0) * BATCH + b];
        float z01 = num_z[(0 * 2 + 1) * BATCH + b];
        float z10 = num_z[(1 * 2 + 0) * BATCH + b];
        float z11 = num_z[(1 * 2 + 1) * BATCH + b];
        float perm0 = z00 + z11;
        float perm1 = z01 + z10;
        float n0, n1;
        if (perm0 >= perm1) { n0 = z00; n1 = z11; }
        else                { n0 = z01; n1 = z10; }
        l = -(n0 - den_z[0 * BATCH + b]) - (n1 - den_z[1 * BATCH + b]);
    }
    #pragma unroll
    for (int o = 32; o > 0; o >>= 1) l += __shfl_down(l, o, 64);
    if (tid == 0) out[0] = l;
}

// ---------------------------------------------------------------------------
extern "C" void kernel_launch(void* const* d_in, const int* in_sizes, int n_in,
                              void* d_out, int out_size, void* d_ws, size_t ws_size,
                              hipStream_t stream) {
    const float* est        = (const float*)d_in[0];
    const int*   seqlen     = (const int*)d_in[1];
    const int*   num_src    = (const int*)d_in[2];
    const int*   num_dst    = (const int*)d_in[3];
    const int*   num_label  = (const int*)d_in[4];
    const float* num_weight = (const float*)d_in[5];
    const float* num_start  = (const float*)d_in[6];
    const float* num_final  = (const float*)d_in[7];
    const int*   den_src    = (const int*)d_in[8];
    const int*   den_dst    = (const int*)d_in[9];
    const int*   den_label  = (const int*)d_in[10];
    const float* den_weight = (const float*)d_in[11];
    const float* den_start  = (const float*)d_in[12];
    const float* den_final  = (const float*)d_in[13];

    char* ws = (char*)d_ws;
    int2*     den_arcs = (int2*)(ws + WS_DEN_ARCS);
    int2*     num_arcs = (int2*)(ws + WS_NUM_ARCS);
    int*      den_cnt  = (int*)(ws + WS_DEN_CNT);
    int*      den_R    = (int*)(ws + WS_DEN_R);
    int*      den_cur  = (int*)(ws + WS_DEN_CUR);
    int*      num_cnt  = (int*)(ws + WS_NUM_CNT);
    int*      num_R    = (int*)(ws + WS_NUM_R);
    int*      num_cur  = (int*)(ws + WS_NUM_CUR);
    float*    galpha   = (float*)(ws + WS_GALPHA);
    unsigned* flags    = (unsigned*)(ws + WS_FLAGS);
    int*      bins     = (int*)(ws + WS_BINS);
    float*    den_z    = (float*)(ws + WS_DEN_Z);
    float*    num_z    = (float*)(ws + WS_NUM_Z);
    int*      bincur   = (int*)(ws + WS_BINCUR);
    int*      pi       = (int*)(ws + WS_PI);
    int*      inv      = (int*)(ws + WS_INV);
    int*      cntp     = (int*)(ws + WS_CNTP);

    zero_ws<<<512, 256, 0, stream>>>((int*)ws, WS_ZERO_INTS);
    hist_den<<<(DEN_ARCS + 255) / 256, 256, 0, stream>>>(den_dst, den_cnt);
    hist_num<<<(NGRAPH * NUM_ARCS + 255) / 256, 256, 0, stream>>>(num_dst, num_cnt);

    // load-balancing permutation for the den graph
    bin_hist<<<(DEN_STATES + 255) / 256, 256, 0, stream>>>(den_cnt, bins);
    bin_scan<<<1, 64, 0, stream>>>(bins, bincur);
    rank_scatter<<<(DEN_STATES + 255) / 256, 256, 0, stream>>>(den_cnt, bincur, pi, inv);
    permute_cnt<<<(DEN_STATES + 255) / 256, 256, 0, stream>>>(den_cnt, inv, cntp);

    scan_den<<<1, 1024, 0, stream>>>(cntp, den_R);
    scan_num<<<NGRAPH, 512, 0, stream>>>(num_cnt, num_R);
    scat_den<<<(DEN_ARCS + 255) / 256, 256, 0, stream>>>(
        den_src, den_dst, den_label, den_weight, den_R, den_cur, pi, den_arcs);
    scat_num<<<(NGRAPH * NUM_ARCS + 255) / 256, 256, 0, stream>>>(
        num_src, num_dst, num_label, num_weight, num_R, num_cur, num_arcs);

    forward_kernel<<<KCH * NSEQ + S_SPK * S_SPK * BATCH, BLK, 0, stream>>>(
        est, seqlen, den_arcs, den_R, den_start, den_final, inv,
        num_arcs, num_R, num_start, num_final,
        galpha, flags, den_z, num_z);

    loss_kernel<<<1, 64, 0, stream>>>(den_z, num_z, (float*)d_out);
}

// Round 3
// 1766.216 us; speedup vs baseline: 1.1378x; 1.1378x over previous
//
#include <hip/hip_runtime.h>
#include <hip/hip_bf16.h>

#define S_SPK 2
#define BATCH 16
#define TMAX 300
#define CLASSES 3000
#define NUM_STATES 400
#define NUM_ARCS 1200
#define DEN_STATES 3000
#define DEN_ARCS 60000

#define BLK 768               // threads per forward block (12 waves)
#define NWAVE 12
#define KCH 4                 // den chunks per sequence
#define CHST 750              // 3000 / 4
#define NSEQ 32               // S_SPK * BATCH
#define NUM_CAP_G 2400        // per graph: 1200 + 3*400
#define NGRAPH 32             // (p,b) graphs

// ---------------- workspace layout (bytes) ----------------
#define WS_DEN_ARCS   0              // 72000*8   = 576000
#define WS_NUM_ARCS   576000         // 32*2400*8 = 614400 -> 1190400
#define WS_DEN_CNT    1190400        // 3000*4    -> 1202400
#define WS_DEN_R      1202400        // 3001*4    -> 1214416 (pad)
#define WS_DEN_CUR    1214416        // 3000*4    -> 1226416
#define WS_NUM_CNT    1226416        // 32*400*4  -> 1277616
#define WS_NUM_R      1277616        // 32*401*4  -> 1328944
#define WS_NUM_CUR    1328944        // 32*400*4  -> 1380144
#define WS_GALPHA     1380144        // 32*2*3000*4 = 768000 -> 2148144 (tagged)
#define WS_FLAGS      2148144        // (unused now) -> 2156336
#define WS_BINS       2156336        // 64*4 -> 2156592  (count histogram)
#define WS_DEN_Z      2156592        // 32 floats -> 2156720
#define WS_NUM_Z      2156720        // 64 floats -> 2156976
#define WS_BINCUR     2156976        // 64*4 -> 2157232
#define WS_PI         2157232        // 3000*4 -> 2169232 (state -> position)
#define WS_INV        2169232        // 3000*4 -> 2181232 (position -> state)
#define WS_CNTP       2181232        // 3000*4 -> 2193232 (cnt by position)
#define WS_ZERO_INTS  (2156592 / 4)  // zero everything below den_z (incl galpha: tag=0)

// ---------------------------------------------------------------------------
__global__ void zero_ws(int* __restrict__ p, int n) {
    int i = blockIdx.x * blockDim.x + threadIdx.x;
    for (; i < n; i += gridDim.x * blockDim.x) p[i] = 0;
}

__global__ void hist_den(const int* __restrict__ dst, int* __restrict__ cnt) {
    int i = blockIdx.x * blockDim.x + threadIdx.x;
    if (i < DEN_ARCS) atomicAdd(&cnt[dst[i]], 1);
}

__global__ void hist_num(const int* __restrict__ dst, int* __restrict__ cnt) {
    int i = blockIdx.x * blockDim.x + threadIdx.x;
    if (i < NGRAPH * NUM_ARCS) {
        int g = i / NUM_ARCS;
        atomicAdd(&cnt[g * NUM_STATES + dst[i]], 1);
    }
}

// ---- load-balancing permutation: counting-sort states by arc count (desc),
// ---- deal round-robin across the 4 chunks so each wave holds like-count states
__global__ void bin_hist(const int* __restrict__ cnt, int* __restrict__ bins) {
    int s = blockIdx.x * blockDim.x + threadIdx.x;
    if (s < DEN_STATES) {
        int c = cnt[s]; if (c > 63) c = 63;
        atomicAdd(&bins[c], 1);
    }
}

// 1 block, 64 threads: bincur[b] = #states with count > b (descending ranks)
__global__ void bin_scan(const int* __restrict__ bins, int* __restrict__ bincur) {
    __shared__ int sb[64];
    int tid = threadIdx.x;
    sb[tid] = bins[tid];
    __syncthreads();
    int sum = 0;
    for (int b = 63; b > tid; --b) sum += sb[b];
    bincur[tid] = sum;
}

__global__ void rank_scatter(const int* __restrict__ cnt, int* __restrict__ bincur,
                             int* __restrict__ pi, int* __restrict__ inv) {
    int s = blockIdx.x * blockDim.x + threadIdx.x;
    if (s < DEN_STATES) {
        int c = cnt[s]; if (c > 63) c = 63;
        int rank = atomicAdd(&bincur[c], 1);          // rank 0 = heaviest
        int pos = (rank & (KCH - 1)) * CHST + (rank >> 2);  // deal across chunks
        pi[s] = pos;
        inv[pos] = s;
    }
}

__global__ void permute_cnt(const int* __restrict__ cnt, const int* __restrict__ inv,
                            int* __restrict__ cntp) {
    int p = blockIdx.x * blockDim.x + threadIdx.x;
    if (p < DEN_STATES) cntp[p] = cnt[inv[p]];
}

// one block, 1024 threads: per-POSITION x4-padded prefix for den CSR
__global__ void scan_den(const int* __restrict__ cnt, int* __restrict__ R) {
    __shared__ int sc[1024];
    int tid = threadIdx.x;
    int c0 = 0, c1 = 0, c2 = 0, p0 = 0, p1 = 0, p2 = 0, pg = 0;
    if (tid < 1000) {
        c0 = cnt[3 * tid]; c1 = cnt[3 * tid + 1]; c2 = cnt[3 * tid + 2];
        p0 = (c0 + 3) & ~3; p1 = (c1 + 3) & ~3; p2 = (c2 + 3) & ~3;
        pg = p0 + p1 + p2;
    }
    sc[tid] = pg; __syncthreads();
    for (int o = 1; o < 1024; o <<= 1) {
        int v = (tid >= o) ? sc[tid - o] : 0;
        __syncthreads(); sc[tid] += v; __syncthreads();
    }
    int ex = sc[tid] - pg;
    if (tid < 1000) {
        R[3 * tid] = ex; R[3 * tid + 1] = ex + p0; R[3 * tid + 2] = ex + p0 + p1;
    }
    if (tid == 1000) R[3000] = ex;  // total
}

// 32 blocks x 512: per-graph padded per-state prefix (num)
__global__ void scan_num(const int* __restrict__ cnt, int* __restrict__ R) {
    __shared__ int sc[512];
    int g = blockIdx.x, tid = threadIdx.x;
    int c = 0, pg = 0;
    if (tid < NUM_STATES) { c = cnt[g * NUM_STATES + tid]; pg = (c + 3) & ~3; }
    sc[tid] = pg; __syncthreads();
    for (int o = 1; o < 512; o <<= 1) {
        int v = (tid >= o) ? sc[tid - o] : 0;
        __syncthreads(); sc[tid] += v; __syncthreads();
    }
    int ex = sc[tid] - pg;
    if (tid <= NUM_STATES) R[g * (NUM_STATES + 1) + tid] = ex;
}

__global__ void scat_den(const int* __restrict__ src, const int* __restrict__ dst,
                         const int* __restrict__ lab, const float* __restrict__ w,
                         const int* __restrict__ R, int* __restrict__ cur,
                         const int* __restrict__ pi, int2* __restrict__ out) {
    int i = blockIdx.x * blockDim.x + threadIdx.x;
    if (i >= DEN_ARCS) return;
    int dpos = pi[dst[i]];
    int spos = pi[src[i]];
    int pos = R[dpos] + atomicAdd(&cur[dpos], 1);
    out[pos] = make_int2(spos | (lab[i] << 16), __float_as_int(__expf(w[i])));
}

__global__ void scat_num(const int* __restrict__ src, const int* __restrict__ dst,
                         const int* __restrict__ lab, const float* __restrict__ w,
                         const int* __restrict__ R, int* __restrict__ cur,
                         int2* __restrict__ out) {
    int i = blockIdx.x * blockDim.x + threadIdx.x;
    if (i >= NGRAPH * NUM_ARCS) return;
    int g = i / NUM_ARCS;
    int d = dst[i];
    int pos = R[g * (NUM_STATES + 1) + d] + atomicAdd(&cur[g * NUM_STATES + d], 1);
    out[g * NUM_CAP_G + pos] =
        make_int2(src[i] | (lab[i] << 16), __float_as_int(__expf(w[i])));
}

// ---------------------------------------------------------------------------
// num forward: single 768-thread block, prob domain, 1 state/thread
// ---------------------------------------------------------------------------
__device__ __forceinline__ void num_fwd(
    const int* __restrict__ R, const int2* __restrict__ arcs,
    const float* __restrict__ start, const float* __restrict__ fin,
    const float* __restrict__ est, int L, float* __restrict__ out,
    float* A0, float* A1, float* p, float* red)
{
    const int tid = threadIdx.x, lane = tid & 63, wid = tid >> 6;

    if (tid < NUM_STATES) A0[tid] = __expf(start[tid]);

    int rs = 0, re = 0;
    if (tid < NUM_STATES) { rs = R[tid]; re = R[tid + 1]; }

    float l0 = est[tid], l1 = est[tid + 768], l2 = est[tid + 1536];
    float l3 = (tid < 696) ? est[tid + 2304] : 0.f;

    float c = 1.f, OFF = 0.f, pend = 0.f;
    const int4* arcs4 = (const int4*)arcs;

    for (int t = 0; t < L; ++t) {
        OFF += pend;
        p[tid] = __expf(l0) * c;        p[tid + 768] = __expf(l1) * c;
        p[tid + 1536] = __expf(l2) * c;
        if (tid < 696) p[tid + 2304] = __expf(l3) * c;
        {
            const float* nr = est + (size_t)((t + 1 < L) ? (t + 1) : t) * CLASSES;
            l0 = nr[tid]; l1 = nr[tid + 768]; l2 = nr[tid + 1536];
            if (tid < 696) l3 = nr[tid + 2304];
        }
        __syncthreads();   // p ready (also protects red[] from prev iter reads)

        const float* Ac = (t & 1) ? A1 : A0;
        float*       An = (t & 1) ? A0 : A1;
        float a0 = 0.f;
        for (int r = rs; r < re; r += 4) {
            int4 q0 = arcs4[(r >> 1)];
            int4 q1 = arcs4[(r >> 1) + 1];
            a0 += Ac[q0.x & 0xffff] * p[((unsigned)q0.x) >> 16] * __int_as_float(q0.y);
            a0 += Ac[q0.z & 0xffff] * p[((unsigned)q0.z) >> 16] * __int_as_float(q0.w);
            a0 += Ac[q1.x & 0xffff] * p[((unsigned)q1.x) >> 16] * __int_as_float(q1.y);
            a0 += Ac[q1.z & 0xffff] * p[((unsigned)q1.z) >> 16] * __int_as_float(q1.w);
        }
        float mymax = 0.f;
        if (tid < NUM_STATES) { An[tid] = a0; mymax = a0; }
        #pragma unroll
        for (int o = 32; o > 0; o >>= 1) mymax = fmaxf(mymax, __shfl_down(mymax, o, 64));
        if (lane == 0) red[wid] = mymax;
        __syncthreads();
        float M = red[0];
        #pragma unroll
        for (int k = 1; k < NWAVE; ++k) M = fmaxf(M, red[k]);
        M = fmaxf(M, 1e-37f);
        c = 1.0f / M;
        pend = __logf(M);
    }

    const float* Af = (L & 1) ? A1 : A0;
    float fs = 0.f;
    if (tid < NUM_STATES) fs = Af[tid] * __expf(fin[tid]);
    __syncthreads();   // red[] settled
    #pragma unroll
    for (int o = 32; o > 0; o >>= 1) fs += __shfl_down(fs, o, 64);
    if (lane == 0) red[wid] = fs;
    __syncthreads();
    if (tid == 0) {
        float s = 0.f;
        #pragma unroll
        for (int k = 0; k < NWAVE; ++k) s += red[k];
        out[0] = OFF + __logf(s);
    }
}

// ---------------------------------------------------------------------------
// Fused forward: blocks [0,128) = den chunk*32+seq; [128,192) = num.
// Den: k=4 chunks exchange alpha per step via LLC with DATA-EMBEDDED TAGS:
// each stored alpha word carries a 2-bit step tag ((t%3)+1, never 0 = the
// zeroed-buffer value) in its mantissa LSBs. No flags, no release fences,
// no store-drain on the publish path: each 4B word is self-validating.
// Each thread polls exactly its own 4 gather words (coalesced per wave).
// S1/S2/red are double-buffered by t&1 -> ONE __syncthreads per step; the
// 1-barrier/step spacing prevents LDS reuse races (a wave must pass barrier
// t+1, which requires all waves to finish step t, before touching a [t&1]
// buffer again). Anti-overrun on galpha: a chunk reaches its t+2 write only
// after observing all t+1 tags, which post-date every consumer's t-reads.
// Tag noise is <=3 ulp and identical in all chunks (max M stays consistent).
// ---------------------------------------------------------------------------
__global__ __launch_bounds__(BLK) void forward_kernel(
    const float* __restrict__ est, const int* __restrict__ seqlen,
    const int2* __restrict__ den_arcs, const int* __restrict__ den_R,
    const float* __restrict__ den_start, const float* __restrict__ den_final,
    const int* __restrict__ den_inv,
    const int2* __restrict__ num_arcs, const int* __restrict__ num_R,
    const float* __restrict__ num_start, const float* __restrict__ num_final,
    float* __restrict__ galpha,
    float* __restrict__ den_z, float* __restrict__ num_z)
{
    __shared__ float S1[2][DEN_STATES];   // den: alpha (double-buffered) | num: A0/A1
    __shared__ float S2[2][CLASSES];      // den: p (double-buffered)     | num: p
    __shared__ float red[2][16];

    const int blk = blockIdx.x;
    const int tid = threadIdx.x, lane = tid & 63, wid = tid >> 6;

    if (blk < KCH * NSEQ) {
        const int seq = blk & 31;        // chunks of a seq share XCD residue
        const int chunk = blk >> 5;
        const int b = seq & 15;
        const int L = seqlen[b];
        const float* est_base = est + (size_t)seq * TMAX * CLASSES;
        const int base = chunk * CHST;
        unsigned* gaU = (unsigned*)galpha;

        int rs = 0, re = 0;
        if (tid < CHST) { rs = den_R[base + tid]; re = den_R[base + tid + 1]; }

        float l0 = est_base[tid], l1 = est_base[tid + 768], l2 = est_base[tid + 1536];
        float l3 = (tid < 696) ? est_base[tid + 2304] : 0.f;

        float OFF = 0.f;
        const int4* arcs4 = (const int4*)den_arcs;

        for (int t = 0; t < L; ++t) {
            const int cur = t & 1;
            float* S1c = S1[cur];
            float* S2c = S2[cur];

            // stage p_raw = exp(llh); prefetch next row (overlaps poll)
            S2c[tid] = __expf(l0); S2c[tid + 768] = __expf(l1); S2c[tid + 1536] = __expf(l2);
            if (tid < 696) S2c[tid + 2304] = __expf(l3);
            {
                const float* nr = est_base + (size_t)((t + 1 < L) ? (t + 1) : t) * CLASSES;
                l0 = nr[tid]; l1 = nr[tid + 768]; l2 = nr[tid + 1536];
                if (tid < 696) l3 = nr[tid + 2304];
            }

            if (t == 0) {
                S1c[tid]        = __expf(den_start[den_inv[tid]]);
                S1c[tid + 768]  = __expf(den_start[den_inv[tid + 768]]);
                S1c[tid + 1536] = __expf(den_start[den_inv[tid + 1536]]);
                if (tid < 696) S1c[tid + 2304] = __expf(den_start[den_inv[tid + 2304]]);
            } else {
                // per-thread data-tag poll on its own 4 gather words
                const unsigned tg = (unsigned)((t - 1) % 3) + 1u;
                const unsigned* gp = gaU + ((size_t)seq * 2 + ((t - 1) & 1)) * DEN_STATES;
                unsigned u0, u1, u2, u3 = tg;   // synthetic match for tid>=696
                for (;;) {
                    u0 = __hip_atomic_load(gp + tid,        __ATOMIC_RELAXED, __HIP_MEMORY_SCOPE_AGENT);
                    u1 = __hip_atomic_load(gp + tid + 768,  __ATOMIC_RELAXED, __HIP_MEMORY_SCOPE_AGENT);
                    u2 = __hip_atomic_load(gp + tid + 1536, __ATOMIC_RELAXED, __HIP_MEMORY_SCOPE_AGENT);
                    if (tid < 696)
                        u3 = __hip_atomic_load(gp + tid + 2304, __ATOMIC_RELAXED, __HIP_MEMORY_SCOPE_AGENT);
                    if ((((u0 & 3u) == tg) && ((u1 & 3u) == tg)) &&
                        (((u2 & 3u) == tg) && ((u3 & 3u) == tg))) break;
                    __builtin_amdgcn_s_sleep(1);
                }
                float x0 = __uint_as_float(u0 & ~3u);
                float x1 = __uint_as_float(u1 & ~3u);
                float x2 = __uint_as_float(u2 & ~3u);
                float x3 = (tid < 696) ? __uint_as_float(u3 & ~3u) : 0.f;
                S1c[tid] = x0; S1c[tid + 768] = x1; S1c[tid + 1536] = x2;
                if (tid < 696) S1c[tid + 2304] = x3;
                // wave-level partial max (block combine deferred to post-arc-loop)
                float mymax = fmaxf(fmaxf(x0, x1), fmaxf(x2, x3));
                #pragma unroll
                for (int o = 32; o > 0; o >>= 1)
                    mymax = fmaxf(mymax, __shfl_down(mymax, o, 64));
                if (lane == 0) red[cur][wid] = mymax;
            }

            __syncthreads();   // THE one barrier: S1c,S2c,red[cur] ready; est drained

            float acc = 0.f;
            for (int r = rs; r < re; r += 4) {
                int4 q0 = arcs4[(r >> 1)];
                int4 q1 = arcs4[(r >> 1) + 1];
                acc += S1c[q0.x & 0xffff] * S2c[((unsigned)q0.x) >> 16] * __int_as_float(q0.y);
                acc += S1c[q0.z & 0xffff] * S2c[((unsigned)q0.z) >> 16] * __int_as_float(q0.w);
                acc += S1c[q1.x & 0xffff] * S2c[((unsigned)q1.x) >> 16] * __int_as_float(q1.y);
                acc += S1c[q1.z & 0xffff] * S2c[((unsigned)q1.z) >> 16] * __int_as_float(q1.w);
            }

            float cM = 1.0f;
            if (t) {
                float M = red[cur][0];
                #pragma unroll
                for (int k = 1; k < NWAVE; ++k) M = fmaxf(M, red[cur][k]);
                M = fmaxf(M, 1e-37f);
                cM = 1.0f / M;
                OFF += __logf(M);
            }

            if (tid < CHST) {
                unsigned uv = (__float_as_uint(acc * cM) & ~3u) | ((unsigned)(t % 3) + 1u);
                __hip_atomic_store(gaU + ((size_t)seq * 2 + cur) * DEN_STATES + base + tid,
                                   uv, __ATOMIC_RELAXED, __HIP_MEMORY_SCOPE_AGENT);
            }
            asm volatile("" ::: "memory");   // pin the store before next poll
        }

        // epilogue: chunk 0 computes logZ from final buffer (data-tag poll)
        if (chunk == 0) {
            __syncthreads();   // all waves past loop; red free for reuse
            const unsigned tg = (unsigned)((L - 1) % 3) + 1u;
            const unsigned* gp = gaU + ((size_t)seq * 2 + ((L - 1) & 1)) * DEN_STATES;
            unsigned u0, u1, u2, u3 = tg;
            for (;;) {
                u0 = __hip_atomic_load(gp + tid,        __ATOMIC_RELAXED, __HIP_MEMORY_SCOPE_AGENT);
                u1 = __hip_atomic_load(gp + tid + 768,  __ATOMIC_RELAXED, __HIP_MEMORY_SCOPE_AGENT);
                u2 = __hip_atomic_load(gp + tid + 1536, __ATOMIC_RELAXED, __HIP_MEMORY_SCOPE_AGENT);
                if (tid < 696)
                    u3 = __hip_atomic_load(gp + tid + 2304, __ATOMIC_RELAXED, __HIP_MEMORY_SCOPE_AGENT);
                if ((((u0 & 3u) == tg) && ((u1 & 3u) == tg)) &&
                    (((u2 & 3u) == tg) && ((u3 & 3u) == tg))) break;
                __builtin_amdgcn_s_sleep(1);
            }
            float fs = __uint_as_float(u0 & ~3u) * __expf(den_final[den_inv[tid]])
                     + __uint_as_float(u1 & ~3u) * __expf(den_final[den_inv[tid + 768]])
                     + __uint_as_float(u2 & ~3u) * __expf(den_final[den_inv[tid + 1536]]);
            if (tid < 696)
                fs += __uint_as_float(u3 & ~3u) * __expf(den_final[den_inv[tid + 2304]]);
            #pragma unroll
            for (int o = 32; o > 0; o >>= 1) fs += __shfl_down(fs, o, 64);
            if (lane == 0) red[0][wid] = fs;
            __syncthreads();
            if (tid == 0) {
                float s = 0.f;
                #pragma unroll
                for (int k = 0; k < NWAVE; ++k) s += red[0][k];
                den_z[seq] = OFF + __logf(s);
            }
        }
    } else {
        const int q = blk - KCH * NSEQ;
        const int b = q & 15;
        const int sp = q >> 4;
        const int s = sp >> 1, pp = sp & 1;
        const int L = seqlen[b];
        const int g = pp * BATCH + b;
        num_fwd(num_R + (size_t)g * (NUM_STATES + 1),
                num_arcs + (size_t)g * NUM_CAP_G,
                num_start + (size_t)g * NUM_STATES,
                num_final + (size_t)g * NUM_STATES,
                est + (size_t)(s * BATCH + b) * TMAX * CLASSES, L, &num_z[q],
                &S1[0][0], &S1[0][1536], &S2[0][0], &red[0][0]);
    }
}

// ---------------------------------------------------------------------------
__global__ void loss_kernel(const float* __restrict__ den_z,
                            const float* __restrict__ num_z,
                            float* __restrict__ out)
{
    int tid = threadIdx.x;
    float l = 0.f;
    if (tid < BATCH) {
        int b = tid;
        float z00 = num_z[(0 * 2 + 0) * BATCH + b];
        float z01 = num_z[(0 * 2 + 1) * BATCH + b];
        float z10 = num_z[(1 * 2 + 0) * BATCH + b];
        float z11 = num_z[(1 * 2 + 1) * BATCH + b];
        float perm0 = z00 + z11;
        float perm1 = z01 + z10;
        float n0, n1;
        if (perm0 >= perm1) { n0 = z00; n1 = z11; }
        else                { n0 = z01; n1 = z10; }
        l = -(n0 - den_z[0 * BATCH + b]) - (n1 - den_z[1 * BATCH + b]);
    }
    #pragma unroll
    for (int o = 32; o > 0; o >>= 1) l += __shfl_down(l, o, 64);
    if (tid == 0) out[0] = l;
}

// ---------------------------------------------------------------------------
extern "C" void kernel_launch(void* const* d_in, const int* in_sizes, int n_in,
                              void* d_out, int out_size, void* d_ws, size_t ws_size,
                              hipStream_t stream) {
    const float* est        = (const float*)d_in[0];
    const int*   seqlen     = (const int*)d_in[1];
    const int*   num_src    = (const int*)d_in[2];
    const int*   num_dst    = (const int*)d_in[3];
    const int*   num_label  = (const int*)d_in[4];
    const float* num_weight = (const float*)d_in[5];
    const float* num_start  = (const float*)d_in[6];
    const float* num_final  = (const float*)d_in[7];
    const int*   den_src    = (const int*)d_in[8];
    const int*   den_dst    = (const int*)d_in[9];
    const int*   den_label  = (const int*)d_in[10];
    const float* den_weight = (const float*)d_in[11];
    const float* den_start  = (const float*)d_in[12];
    const float* den_final  = (const float*)d_in[13];

    char* ws = (char*)d_ws;
    int2*     den_arcs = (int2*)(ws + WS_DEN_ARCS);
    int2*     num_arcs = (int2*)(ws + WS_NUM_ARCS);
    int*      den_cnt  = (int*)(ws + WS_DEN_CNT);
    int*      den_R    = (int*)(ws + WS_DEN_R);
    int*      den_cur  = (int*)(ws + WS_DEN_CUR);
    int*      num_cnt  = (int*)(ws + WS_NUM_CNT);
    int*      num_R    = (int*)(ws + WS_NUM_R);
    int*      num_cur  = (int*)(ws + WS_NUM_CUR);
    float*    galpha   = (float*)(ws + WS_GALPHA);
    int*      bins     = (int*)(ws + WS_BINS);
    float*    den_z    = (float*)(ws + WS_DEN_Z);
    float*    num_z    = (float*)(ws + WS_NUM_Z);
    int*      bincur   = (int*)(ws + WS_BINCUR);
    int*      pi       = (int*)(ws + WS_PI);
    int*      inv      = (int*)(ws + WS_INV);
    int*      cntp     = (int*)(ws + WS_CNTP);

    zero_ws<<<512, 256, 0, stream>>>((int*)ws, WS_ZERO_INTS);
    hist_den<<<(DEN_ARCS + 255) / 256, 256, 0, stream>>>(den_dst, den_cnt);
    hist_num<<<(NGRAPH * NUM_ARCS + 255) / 256, 256, 0, stream>>>(num_dst, num_cnt);

    // load-balancing permutation for the den graph
    bin_hist<<<(DEN_STATES + 255) / 256, 256, 0, stream>>>(den_cnt, bins);
    bin_scan<<<1, 64, 0, stream>>>(bins, bincur);
    rank_scatter<<<(DEN_STATES + 255) / 256, 256, 0, stream>>>(den_cnt, bincur, pi, inv);
    permute_cnt<<<(DEN_STATES + 255) / 256, 256, 0, stream>>>(den_cnt, inv, cntp);

    scan_den<<<1, 1024, 0, stream>>>(cntp, den_R);
    scan_num<<<NGRAPH, 512, 0, stream>>>(num_cnt, num_R);
    scat_den<<<(DEN_ARCS + 255) / 256, 256, 0, stream>>>(
        den_src, den_dst, den_label, den_weight, den_R, den_cur, pi, den_arcs);
    scat_num<<<(NGRAPH * NUM_ARCS + 255) / 256, 256, 0, stream>>>(
        num_src, num_dst, num_label, num_weight, num_R, num_cur, num_arcs);

    forward_kernel<<<KCH * NSEQ + S_SPK * S_SPK * BATCH, BLK, 0, stream>>>(
        est, seqlen, den_arcs, den_R, den_start, den_final, inv,
        num_arcs, num_R, num_start, num_final,
        galpha, den_z, num_z);

    loss_kernel<<<1, 64, 0, stream>>>(den_z, num_z, (float*)d_out);
}

// Round 4
// 1602.154 us; speedup vs baseline: 1.2543x; 1.1024x over previous
//
#include <hip/hip_runtime.h>
#include <hip/hip_bf16.h>

#define S_SPK 2
#define BATCH 16
#define TMAX 300
#define CLASSES 3000
#define NUM_STATES 400
#define NUM_ARCS 1200
#define DEN_STATES 3000
#define DEN_ARCS 60000

#define BLK 768               // threads per forward block (12 waves)
#define NWAVE 12
#define KCH 4                 // den chunks per sequence
#define CHST 750              // 3000 / 4
#define NSEQ 32               // S_SPK * BATCH
#define NUM_CAP_G 2400        // per graph: 1200 + 3*400
#define NGRAPH 32             // (p,b) graphs

// ---------------- workspace layout (bytes) ----------------
#define WS_DEN_ARCS   0              // 72000*8   = 576000
#define WS_NUM_ARCS   576000         // 32*2400*8 = 614400 -> 1190400
#define WS_DEN_CNT    1190400        // 3000*4    -> 1202400
#define WS_DEN_R      1202400        // 3001*4    -> 1214416 (pad)
#define WS_DEN_CUR    1214416        // 3000*4    -> 1226416
#define WS_NUM_CNT    1226416        // 32*400*4  -> 1277616
#define WS_NUM_R      1277616        // 32*401*4  -> 1328944
#define WS_NUM_CUR    1328944        // 32*400*4  -> 1380144
#define WS_GALPHA     1380144        // 32*2*3000*4 = 768000 -> 2148144 (tagged)
#define WS_FLAGS      2148144        // (unused now) -> 2156336
#define WS_BINS       2156336        // 64*4 -> 2156592  (count histogram)
#define WS_DEN_Z      2156592        // 32 floats -> 2156720
#define WS_NUM_Z      2156720        // 64 floats -> 2156976
#define WS_BINCUR     2156976        // 64*4 -> 2157232
#define WS_PI         2157232        // 3000*4 -> 2169232 (state -> position)
#define WS_INV        2169232        // 3000*4 -> 2181232 (position -> state)
#define WS_CNTP       2181232        // 3000*4 -> 2193232 (cnt by position)
#define WS_ZERO_INTS  (2156592 / 4)  // zero everything below den_z (incl galpha: tag=0)

// ---------------------------------------------------------------------------
__global__ void zero_ws(int* __restrict__ p, int n) {
    int i = blockIdx.x * blockDim.x + threadIdx.x;
    for (; i < n; i += gridDim.x * blockDim.x) p[i] = 0;
}

__global__ void hist_den(const int* __restrict__ dst, int* __restrict__ cnt) {
    int i = blockIdx.x * blockDim.x + threadIdx.x;
    if (i < DEN_ARCS) atomicAdd(&cnt[dst[i]], 1);
}

__global__ void hist_num(const int* __restrict__ dst, int* __restrict__ cnt) {
    int i = blockIdx.x * blockDim.x + threadIdx.x;
    if (i < NGRAPH * NUM_ARCS) {
        int g = i / NUM_ARCS;
        atomicAdd(&cnt[g * NUM_STATES + dst[i]], 1);
    }
}

// ---- load-balancing permutation: counting-sort states by arc count (desc),
// ---- deal round-robin across the 4 chunks so each wave holds like-count states
__global__ void bin_hist(const int* __restrict__ cnt, int* __restrict__ bins) {
    int s = blockIdx.x * blockDim.x + threadIdx.x;
    if (s < DEN_STATES) {
        int c = cnt[s]; if (c > 63) c = 63;
        atomicAdd(&bins[c], 1);
    }
}

// 1 block, 64 threads: bincur[b] = #states with count > b (descending ranks)
__global__ void bin_scan(const int* __restrict__ bins, int* __restrict__ bincur) {
    __shared__ int sb[64];
    int tid = threadIdx.x;
    sb[tid] = bins[tid];
    __syncthreads();
    int sum = 0;
    for (int b = 63; b > tid; --b) sum += sb[b];
    bincur[tid] = sum;
}

__global__ void rank_scatter(const int* __restrict__ cnt, int* __restrict__ bincur,
                             int* __restrict__ pi, int* __restrict__ inv) {
    int s = blockIdx.x * blockDim.x + threadIdx.x;
    if (s < DEN_STATES) {
        int c = cnt[s]; if (c > 63) c = 63;
        int rank = atomicAdd(&bincur[c], 1);          // rank 0 = heaviest
        int pos = (rank & (KCH - 1)) * CHST + (rank >> 2);  // deal across chunks
        pi[s] = pos;
        inv[pos] = s;
    }
}

__global__ void permute_cnt(const int* __restrict__ cnt, const int* __restrict__ inv,
                            int* __restrict__ cntp) {
    int p = blockIdx.x * blockDim.x + threadIdx.x;
    if (p < DEN_STATES) cntp[p] = cnt[inv[p]];
}

// one block, 1024 threads: per-POSITION x4-padded prefix for den CSR
__global__ void scan_den(const int* __restrict__ cnt, int* __restrict__ R) {
    __shared__ int sc[1024];
    int tid = threadIdx.x;
    int c0 = 0, c1 = 0, c2 = 0, p0 = 0, p1 = 0, p2 = 0, pg = 0;
    if (tid < 1000) {
        c0 = cnt[3 * tid]; c1 = cnt[3 * tid + 1]; c2 = cnt[3 * tid + 2];
        p0 = (c0 + 3) & ~3; p1 = (c1 + 3) & ~3; p2 = (c2 + 3) & ~3;
        pg = p0 + p1 + p2;
    }
    sc[tid] = pg; __syncthreads();
    for (int o = 1; o < 1024; o <<= 1) {
        int v = (tid >= o) ? sc[tid - o] : 0;
        __syncthreads(); sc[tid] += v; __syncthreads();
    }
    int ex = sc[tid] - pg;
    if (tid < 1000) {
        R[3 * tid] = ex; R[3 * tid + 1] = ex + p0; R[3 * tid + 2] = ex + p0 + p1;
    }
    if (tid == 1000) R[3000] = ex;  // total
}

// 32 blocks x 512: per-graph padded per-state prefix (num)
__global__ void scan_num(const int* __restrict__ cnt, int* __restrict__ R) {
    __shared__ int sc[512];
    int g = blockIdx.x, tid = threadIdx.x;
    int c = 0, pg = 0;
    if (tid < NUM_STATES) { c = cnt[g * NUM_STATES + tid]; pg = (c + 3) & ~3; }
    sc[tid] = pg; __syncthreads();
    for (int o = 1; o < 512; o <<= 1) {
        int v = (tid >= o) ? sc[tid - o] : 0;
        __syncthreads(); sc[tid] += v; __syncthreads();
    }
    int ex = sc[tid] - pg;
    if (tid <= NUM_STATES) R[g * (NUM_STATES + 1) + tid] = ex;
}

__global__ void scat_den(const int* __restrict__ src, const int* __restrict__ dst,
                         const int* __restrict__ lab, const float* __restrict__ w,
                         const int* __restrict__ R, int* __restrict__ cur,
                         const int* __restrict__ pi, int2* __restrict__ out) {
    int i = blockIdx.x * blockDim.x + threadIdx.x;
    if (i >= DEN_ARCS) return;
    int dpos = pi[dst[i]];
    int spos = pi[src[i]];
    int pos = R[dpos] + atomicAdd(&cur[dpos], 1);
    out[pos] = make_int2(spos | (lab[i] << 16), __float_as_int(__expf(w[i])));
}

__global__ void scat_num(const int* __restrict__ src, const int* __restrict__ dst,
                         const int* __restrict__ lab, const float* __restrict__ w,
                         const int* __restrict__ R, int* __restrict__ cur,
                         int2* __restrict__ out) {
    int i = blockIdx.x * blockDim.x + threadIdx.x;
    if (i >= NGRAPH * NUM_ARCS) return;
    int g = i / NUM_ARCS;
    int d = dst[i];
    int pos = R[g * (NUM_STATES + 1) + d] + atomicAdd(&cur[g * NUM_STATES + d], 1);
    out[g * NUM_CAP_G + pos] =
        make_int2(src[i] | (lab[i] << 16), __float_as_int(__expf(w[i])));
}

// ---------------------------------------------------------------------------
// num forward: single 768-thread block, prob domain, 1 state/thread
// ---------------------------------------------------------------------------
__device__ __forceinline__ void num_fwd(
    const int* __restrict__ R, const int2* __restrict__ arcs,
    const float* __restrict__ start, const float* __restrict__ fin,
    const float* __restrict__ est, int L, float* __restrict__ out,
    float* A0, float* A1, float* p, float* red)
{
    const int tid = threadIdx.x, lane = tid & 63, wid = tid >> 6;

    if (tid < NUM_STATES) A0[tid] = __expf(start[tid]);

    int rs = 0, re = 0;
    if (tid < NUM_STATES) { rs = R[tid]; re = R[tid + 1]; }

    float l0 = est[tid], l1 = est[tid + 768], l2 = est[tid + 1536];
    float l3 = (tid < 696) ? est[tid + 2304] : 0.f;

    float c = 1.f, OFF = 0.f, pend = 0.f;
    const int4* arcs4 = (const int4*)arcs;

    for (int t = 0; t < L; ++t) {
        OFF += pend;
        p[tid] = __expf(l0) * c;        p[tid + 768] = __expf(l1) * c;
        p[tid + 1536] = __expf(l2) * c;
        if (tid < 696) p[tid + 2304] = __expf(l3) * c;
        {
            const float* nr = est + (size_t)((t + 1 < L) ? (t + 1) : t) * CLASSES;
            l0 = nr[tid]; l1 = nr[tid + 768]; l2 = nr[tid + 1536];
            if (tid < 696) l3 = nr[tid + 2304];
        }
        __syncthreads();   // p ready (also protects red[] from prev iter reads)

        const float* Ac = (t & 1) ? A1 : A0;
        float*       An = (t & 1) ? A0 : A1;
        float a0 = 0.f;
        for (int r = rs; r < re; r += 4) {
            int4 q0 = arcs4[(r >> 1)];
            int4 q1 = arcs4[(r >> 1) + 1];
            a0 += Ac[q0.x & 0xffff] * p[((unsigned)q0.x) >> 16] * __int_as_float(q0.y);
            a0 += Ac[q0.z & 0xffff] * p[((unsigned)q0.z) >> 16] * __int_as_float(q0.w);
            a0 += Ac[q1.x & 0xffff] * p[((unsigned)q1.x) >> 16] * __int_as_float(q1.y);
            a0 += Ac[q1.z & 0xffff] * p[((unsigned)q1.z) >> 16] * __int_as_float(q1.w);
        }
        float mymax = 0.f;
        if (tid < NUM_STATES) { An[tid] = a0; mymax = a0; }
        #pragma unroll
        for (int o = 32; o > 0; o >>= 1) mymax = fmaxf(mymax, __shfl_down(mymax, o, 64));
        if (lane == 0) red[wid] = mymax;
        __syncthreads();
        float M = red[0];
        #pragma unroll
        for (int k = 1; k < NWAVE; ++k) M = fmaxf(M, red[k]);
        M = fmaxf(M, 1e-37f);
        c = 1.0f / M;
        pend = __logf(M);
    }

    const float* Af = (L & 1) ? A1 : A0;
    float fs = 0.f;
    if (tid < NUM_STATES) fs = Af[tid] * __expf(fin[tid]);
    __syncthreads();   // red[] settled
    #pragma unroll
    for (int o = 32; o > 0; o >>= 1) fs += __shfl_down(fs, o, 64);
    if (lane == 0) red[wid] = fs;
    __syncthreads();
    if (tid == 0) {
        float s = 0.f;
        #pragma unroll
        for (int k = 0; k < NWAVE; ++k) s += red[k];
        out[0] = OFF + __logf(s);
    }
}

// ---------------------------------------------------------------------------
// Fused forward: blocks [0,128) = den chunk*32+seq; [128,192) = num.
// Den: k=4 chunks exchange alpha per step via LLC with DATA-EMBEDDED TAGS
// (2 mantissa LSBs = (t%3)+1; never 0 = zeroed buffer). One barrier/step,
// double-buffered S1/S2/red. R4: arc loop is depth-2 software-pipelined
// (prefetch 2 iterations ahead; first 4 int4 issued BEFORE the poll so L2
// latency hides under the spin); cM computed before the arc loop so the
// galpha store issues immediately after the last FMA; red combined via
// 3x float4 instead of 12 scalar LDS reads.
// ---------------------------------------------------------------------------
__global__ __launch_bounds__(BLK) void forward_kernel(
    const float* __restrict__ est, const int* __restrict__ seqlen,
    const int2* __restrict__ den_arcs, const int* __restrict__ den_R,
    const float* __restrict__ den_start, const float* __restrict__ den_final,
    const int* __restrict__ den_inv,
    const int2* __restrict__ num_arcs, const int* __restrict__ num_R,
    const float* __restrict__ num_start, const float* __restrict__ num_final,
    float* __restrict__ galpha,
    float* __restrict__ den_z, float* __restrict__ num_z)
{
    __shared__ float S1[2][DEN_STATES];   // den: alpha (double-buffered) | num: A0/A1
    __shared__ float S2[2][CLASSES];      // den: p (double-buffered)     | num: p
    __shared__ float red[2][16];

    const int blk = blockIdx.x;
    const int tid = threadIdx.x, lane = tid & 63, wid = tid >> 6;

    if (blk < KCH * NSEQ) {
        const int seq = blk & 31;        // chunks of a seq share XCD residue
        const int chunk = blk >> 5;
        const int b = seq & 15;
        const int L = seqlen[b];
        const float* est_base = est + (size_t)seq * TMAX * CLASSES;
        const int base = chunk * CHST;
        unsigned* gaU = (unsigned*)galpha;

        int rs = 0, re = 0;
        if (tid < CHST) { rs = den_R[base + tid]; re = den_R[base + tid + 1]; }
        const int4* arcs4 = (const int4*)den_arcs;
        const int4* ap = arcs4 + (rs >> 1);          // per-thread arc stream base
        const int n4 = (re - rs) >> 2;               // iterations (4 slots each)

        float l0 = est_base[tid], l1 = est_base[tid + 768], l2 = est_base[tid + 1536];
        float l3 = (tid < 696) ? est_base[tid + 2304] : 0.f;

        float OFF = 0.f;

        for (int t = 0; t < L; ++t) {
            const int cur = t & 1;
            float* S1c = S1[cur];
            float* S2c = S2[cur];

            // stage p_raw = exp(llh); prefetch next row (overlaps poll)
            S2c[tid] = __expf(l0); S2c[tid + 768] = __expf(l1); S2c[tid + 1536] = __expf(l2);
            if (tid < 696) S2c[tid + 2304] = __expf(l3);
            {
                const float* nr = est_base + (size_t)((t + 1 < L) ? (t + 1) : t) * CLASSES;
                l0 = nr[tid]; l1 = nr[tid + 768]; l2 = nr[tid + 1536];
                if (tid < 696) l3 = nr[tid + 2304];
            }

            // issue the first two arc-iterations' loads NOW: their ~L2 latency
            // hides under the poll + barrier (prefetch overrun stays inside the
            // padded arc buffer; values are never consumed past n4 iterations)
            int4 a0 = ap[0], a1 = ap[1], b0 = ap[2], b1 = ap[3];

            if (t == 0) {
                S1c[tid]        = __expf(den_start[den_inv[tid]]);
                S1c[tid + 768]  = __expf(den_start[den_inv[tid + 768]]);
                S1c[tid + 1536] = __expf(den_start[den_inv[tid + 1536]]);
                if (tid < 696) S1c[tid + 2304] = __expf(den_start[den_inv[tid + 2304]]);
            } else {
                // per-thread data-tag poll on its own 4 gather words
                const unsigned tg = (unsigned)((t - 1) % 3) + 1u;
                const unsigned* gp = gaU + ((size_t)seq * 2 + ((t - 1) & 1)) * DEN_STATES;
                unsigned u0, u1, u2, u3 = tg;   // synthetic match for tid>=696
                for (;;) {
                    u0 = __hip_atomic_load(gp + tid,        __ATOMIC_RELAXED, __HIP_MEMORY_SCOPE_AGENT);
                    u1 = __hip_atomic_load(gp + tid + 768,  __ATOMIC_RELAXED, __HIP_MEMORY_SCOPE_AGENT);
                    u2 = __hip_atomic_load(gp + tid + 1536, __ATOMIC_RELAXED, __HIP_MEMORY_SCOPE_AGENT);
                    if (tid < 696)
                        u3 = __hip_atomic_load(gp + tid + 2304, __ATOMIC_RELAXED, __HIP_MEMORY_SCOPE_AGENT);
                    if ((((u0 & 3u) == tg) && ((u1 & 3u) == tg)) &&
                        (((u2 & 3u) == tg) && ((u3 & 3u) == tg))) break;
                    __builtin_amdgcn_s_sleep(1);
                }
                float x0 = __uint_as_float(u0 & ~3u);
                float x1 = __uint_as_float(u1 & ~3u);
                float x2 = __uint_as_float(u2 & ~3u);
                float x3 = (tid < 696) ? __uint_as_float(u3 & ~3u) : 0.f;
                S1c[tid] = x0; S1c[tid + 768] = x1; S1c[tid + 1536] = x2;
                if (tid < 696) S1c[tid + 2304] = x3;
                // wave-level partial max (block combine deferred past barrier)
                float mymax = fmaxf(fmaxf(x0, x1), fmaxf(x2, x3));
                #pragma unroll
                for (int o = 32; o > 0; o >>= 1)
                    mymax = fmaxf(mymax, __shfl_down(mymax, o, 64));
                if (lane == 0) red[cur][wid] = mymax;
            }

            __syncthreads();   // THE one barrier: S1c,S2c,red[cur] ready

            // combine block max FIRST (3x b128 broadcast reads), so the store
            // can issue immediately after the arc loop's last FMA
            float cM = 1.0f;
            if (t) {
                const float4* r4 = (const float4*)red[cur];
                float4 ra = r4[0], rb = r4[1], rc = r4[2];
                float M = fmaxf(fmaxf(fmaxf(ra.x, ra.y), fmaxf(ra.z, ra.w)),
                         fmaxf(fmaxf(fmaxf(rb.x, rb.y), fmaxf(rb.z, rb.w)),
                               fmaxf(fmaxf(rc.x, rc.y), fmaxf(rc.z, rc.w))));
                M = fmaxf(M, 1e-37f);
                cM = 1.0f / M;
                OFF += __logf(M);
            }

            // depth-2 software-pipelined arc loop
            float acc = 0.f;
            for (int i = 0; i < n4; ++i) {
                int4 p0 = ap[2 * i + 4], p1 = ap[2 * i + 5];   // 2 iters ahead
                acc += S1c[a0.x & 0xffff] * S2c[((unsigned)a0.x) >> 16] * __int_as_float(a0.y);
                acc += S1c[a0.z & 0xffff] * S2c[((unsigned)a0.z) >> 16] * __int_as_float(a0.w);
                acc += S1c[a1.x & 0xffff] * S2c[((unsigned)a1.x) >> 16] * __int_as_float(a1.y);
                acc += S1c[a1.z & 0xffff] * S2c[((unsigned)a1.z) >> 16] * __int_as_float(a1.w);
                a0 = b0; a1 = b1; b0 = p0; b1 = p1;
            }

            if (tid < CHST) {
                unsigned uv = (__float_as_uint(acc * cM) & ~3u) | ((unsigned)(t % 3) + 1u);
                __hip_atomic_store(gaU + ((size_t)seq * 2 + cur) * DEN_STATES + base + tid,
                                   uv, __ATOMIC_RELAXED, __HIP_MEMORY_SCOPE_AGENT);
            }
            asm volatile("" ::: "memory");   // pin the store before next poll
        }

        // epilogue: chunk 0 computes logZ from final buffer (data-tag poll)
        if (chunk == 0) {
            __syncthreads();   // all waves past loop; red free for reuse
            const unsigned tg = (unsigned)((L - 1) % 3) + 1u;
            const unsigned* gp = gaU + ((size_t)seq * 2 + ((L - 1) & 1)) * DEN_STATES;
            unsigned u0, u1, u2, u3 = tg;
            for (;;) {
                u0 = __hip_atomic_load(gp + tid,        __ATOMIC_RELAXED, __HIP_MEMORY_SCOPE_AGENT);
                u1 = __hip_atomic_load(gp + tid + 768,  __ATOMIC_RELAXED, __HIP_MEMORY_SCOPE_AGENT);
                u2 = __hip_atomic_load(gp + tid + 1536, __ATOMIC_RELAXED, __HIP_MEMORY_SCOPE_AGENT);
                if (tid < 696)
                    u3 = __hip_atomic_load(gp + tid + 2304, __ATOMIC_RELAXED, __HIP_MEMORY_SCOPE_AGENT);
                if ((((u0 & 3u) == tg) && ((u1 & 3u) == tg)) &&
                    (((u2 & 3u) == tg) && ((u3 & 3u) == tg))) break;
                __builtin_amdgcn_s_sleep(1);
            }
            float fs = __uint_as_float(u0 & ~3u) * __expf(den_final[den_inv[tid]])
                     + __uint_as_float(u1 & ~3u) * __expf(den_final[den_inv[tid + 768]])
                     + __uint_as_float(u2 & ~3u) * __expf(den_final[den_inv[tid + 1536]]);
            if (tid < 696)
                fs += __uint_as_float(u3 & ~3u) * __expf(den_final[den_inv[tid + 2304]]);
            #pragma unroll
            for (int o = 32; o > 0; o >>= 1) fs += __shfl_down(fs, o, 64);
            if (lane == 0) red[0][wid] = fs;
            __syncthreads();
            if (tid == 0) {
                float s = 0.f;
                #pragma unroll
                for (int k = 0; k < NWAVE; ++k) s += red[0][k];
                den_z[seq] = OFF + __logf(s);
            }
        }
    } else {
        const int q = blk - KCH * NSEQ;
        const int b = q & 15;
        const int sp = q >> 4;
        const int s = sp >> 1, pp = sp & 1;
        const int L = seqlen[b];
        const int g = pp * BATCH + b;
        num_fwd(num_R + (size_t)g * (NUM_STATES + 1),
                num_arcs + (size_t)g * NUM_CAP_G,
                num_start + (size_t)g * NUM_STATES,
                num_final + (size_t)g * NUM_STATES,
                est + (size_t)(s * BATCH + b) * TMAX * CLASSES, L, &num_z[q],
                &S1[0][0], &S1[0][1536], &S2[0][0], &red[0][0]);
    }
}

// ---------------------------------------------------------------------------
__global__ void loss_kernel(const float* __restrict__ den_z,
                            const float* __restrict__ num_z,
                            float* __restrict__ out)
{
    int tid = threadIdx.x;
    float l = 0.f;
    if (tid < BATCH) {
        int b = tid;
        float z00 = num_z[(0 * 2 + 0) * BATCH + b];
        float z01 = num_z[(0 * 2 + 1) * BATCH + b];
        float z10 = num_z[(1 * 2 + 0) * BATCH + b];
        float z11 = num_z[(1 * 2 + 1) * BATCH + b];
        float perm0 = z00 + z11;
        float perm1 = z01 + z10;
        float n0, n1;
        if (perm0 >= perm1) { n0 = z00; n1 = z11; }
        else                { n0 = z01; n1 = z10; }
        l = -(n0 - den_z[0 * BATCH + b]) - (n1 - den_z[1 * BATCH + b]);
    }
    #pragma unroll
    for (int o = 32; o > 0; o >>= 1) l += __shfl_down(l, o, 64);
    if (tid == 0) out[0] = l;
}

// ---------------------------------------------------------------------------
extern "C" void kernel_launch(void* const* d_in, const int* in_sizes, int n_in,
                              void* d_out, int out_size, void* d_ws, size_t ws_size,
                              hipStream_t stream) {
    const float* est        = (const float*)d_in[0];
    const int*   seqlen     = (const int*)d_in[1];
    const int*   num_src    = (const int*)d_in[2];
    const int*   num_dst    = (const int*)d_in[3];
    const int*   num_label  = (const int*)d_in[4];
    const float* num_weight = (const float*)d_in[5];
    const float* num_start  = (const float*)d_in[6];
    const float* num_final  = (const float*)d_in[7];
    const int*   den_src    = (const int*)d_in[8];
    const int*   den_dst    = (const int*)d_in[9];
    const int*   den_label  = (const int*)d_in[10];
    const float* den_weight = (const float*)d_in[11];
    const float* den_start  = (const float*)d_in[12];
    const float* den_final  = (const float*)d_in[13];

    char* ws = (char*)d_ws;
    int2*     den_arcs = (int2*)(ws + WS_DEN_ARCS);
    int2*     num_arcs = (int2*)(ws + WS_NUM_ARCS);
    int*      den_cnt  = (int*)(ws + WS_DEN_CNT);
    int*      den_R    = (int*)(ws + WS_DEN_R);
    int*      den_cur  = (int*)(ws + WS_DEN_CUR);
    int*      num_cnt  = (int*)(ws + WS_NUM_CNT);
    int*      num_R    = (int*)(ws + WS_NUM_R);
    int*      num_cur  = (int*)(ws + WS_NUM_CUR);
    float*    galpha   = (float*)(ws + WS_GALPHA);
    int*      bins     = (int*)(ws + WS_BINS);
    float*    den_z    = (float*)(ws + WS_DEN_Z);
    float*    num_z    = (float*)(ws + WS_NUM_Z);
    int*      bincur   = (int*)(ws + WS_BINCUR);
    int*      pi       = (int*)(ws + WS_PI);
    int*      inv      = (int*)(ws + WS_INV);
    int*      cntp     = (int*)(ws + WS_CNTP);

    zero_ws<<<512, 256, 0, stream>>>((int*)ws, WS_ZERO_INTS);
    hist_den<<<(DEN_ARCS + 255) / 256, 256, 0, stream>>>(den_dst, den_cnt);
    hist_num<<<(NGRAPH * NUM_ARCS + 255) / 256, 256, 0, stream>>>(num_dst, num_cnt);

    // load-balancing permutation for the den graph
    bin_hist<<<(DEN_STATES + 255) / 256, 256, 0, stream>>>(den_cnt, bins);
    bin_scan<<<1, 64, 0, stream>>>(bins, bincur);
    rank_scatter<<<(DEN_STATES + 255) / 256, 256, 0, stream>>>(den_cnt, bincur, pi, inv);
    permute_cnt<<<(DEN_STATES + 255) / 256, 256, 0, stream>>>(den_cnt, inv, cntp);

    scan_den<<<1, 1024, 0, stream>>>(cntp, den_R);
    scan_num<<<NGRAPH, 512, 0, stream>>>(num_cnt, num_R);
    scat_den<<<(DEN_ARCS + 255) / 256, 256, 0, stream>>>(
        den_src, den_dst, den_label, den_weight, den_R, den_cur, pi, den_arcs);
    scat_num<<<(NGRAPH * NUM_ARCS + 255) / 256, 256, 0, stream>>>(
        num_src, num_dst, num_label, num_weight, num_R, num_cur, num_arcs);

    forward_kernel<<<KCH * NSEQ + S_SPK * S_SPK * BATCH, BLK, 0, stream>>>(
        est, seqlen, den_arcs, den_R, den_start, den_final, inv,
        num_arcs, num_R, num_start, num_final,
        galpha, den_z, num_z);

    loss_kernel<<<1, 64, 0, stream>>>(den_z, num_z, (float*)d_out);
}

// Round 5
// 1562.541 us; speedup vs baseline: 1.2861x; 1.0254x over previous
//
#include <hip/hip_runtime.h>
#include <hip/hip_bf16.h>

#define S_SPK 2
#define BATCH 16
#define TMAX 300
#define CLASSES 3000
#define NUM_STATES 400
#define NUM_ARCS 1200
#define DEN_STATES 3000
#define DEN_ARCS 60000

#define BLK 768               // threads per forward block (12 waves)
#define NWAVE 12
#define KCH 6                 // den chunks per sequence (6*32 + 64 = 256 blocks = 1/CU)
#define CHST 500              // 3000 / 6
#define NSEQ 32               // S_SPK * BATCH
#define NUM_CAP_G 2400        // per graph: 1200 + 3*400
#define NGRAPH 32             // (p,b) graphs

// ---------------- workspace layout (bytes) ----------------
#define WS_DEN_ARCS   0              // 72000*8   = 576000
#define WS_NUM_ARCS   576000         // 32*2400*8 = 614400 -> 1190400
#define WS_DEN_CNT    1190400        // 3000*4    -> 1202400
#define WS_DEN_R      1202400        // 3001*4    -> 1214416 (pad)
#define WS_DEN_CUR    1214416        // 3000*4    -> 1226416
#define WS_NUM_CNT    1226416        // 32*400*4  -> 1277616
#define WS_NUM_R      1277616        // 32*401*4  -> 1328944
#define WS_NUM_CUR    1328944        // 32*400*4  -> 1380144
#define WS_GALPHA     1380144        // 32*2*3000*4 = 768000 -> 2148144 (tagged)
#define WS_FLAGS      2148144        // (unused) -> 2156336
#define WS_BINS       2156336        // (unused) -> 2156592
#define WS_DEN_Z      2156592        // 32 floats -> 2156720
#define WS_NUM_Z      2156720        // 64 floats -> 2156976
#define WS_BINCUR     2156976        // (unused) -> 2157232
#define WS_PI         2157232        // 3000*4 -> 2169232 (state -> position)
#define WS_INV        2169232        // 3000*4 -> 2181232 (position -> state)
#define WS_ZERO_INTS  (2156592 / 4)  // zero everything below den_z (incl galpha: tag=0)

// ---------------------------------------------------------------------------
__global__ void zero_ws(int* __restrict__ p, int n) {
    int i = blockIdx.x * blockDim.x + threadIdx.x;
    for (; i < n; i += gridDim.x * blockDim.x) p[i] = 0;
}

// fused histograms (den + num)
__global__ void hist_all(const int* __restrict__ dden, int* __restrict__ dcnt,
                         const int* __restrict__ dnum, int* __restrict__ ncnt) {
    int i = blockIdx.x * blockDim.x + threadIdx.x;
    if (i < DEN_ARCS) atomicAdd(&dcnt[dden[i]], 1);
    if (i < NGRAPH * NUM_ARCS) {
        int g = i / NUM_ARCS;
        atomicAdd(&ncnt[g * NUM_STATES + dnum[i]], 1);
    }
}

// ---------------------------------------------------------------------------
// Fused den preprocessing, one 1024-thread block:
//  1) histogram of arc counts (LDS bins)
//  2) suffix-scan -> rank base per count (descending ranks)
//  3) counting-sort states by count desc, deal round-robin across the KCH
//     chunks -> pi (state->pos), inv (pos->state)   [global; visible in-block
//     after __syncthreads]
//  4) per-POSITION x4-padded prefix -> den CSR row offsets R
// ---------------------------------------------------------------------------
__global__ void prep_den(const int* __restrict__ cnt, int* __restrict__ pi,
                         int* __restrict__ inv, int* __restrict__ R) {
    __shared__ int bins[64], bcur[64], sc[1024];
    const int tid = threadIdx.x;

    if (tid < 64) bins[tid] = 0;
    __syncthreads();

    int c0 = 0, c1 = 0, c2 = 0;
    if (tid < 1000) {
        c0 = cnt[3 * tid]; c1 = cnt[3 * tid + 1]; c2 = cnt[3 * tid + 2];
        atomicAdd(&bins[min(c0, 63)], 1);
        atomicAdd(&bins[min(c1, 63)], 1);
        atomicAdd(&bins[min(c2, 63)], 1);
    }
    __syncthreads();

    if (tid < 64) {
        int sum = 0;
        for (int b = 63; b > tid; --b) sum += bins[b];
        bcur[tid] = sum;
    }
    __syncthreads();

    if (tid < 1000) {
        int cc[3] = { c0, c1, c2 };
        #pragma unroll
        for (int j = 0; j < 3; ++j) {
            int c = min(cc[j], 63);
            int rank = atomicAdd(&bcur[c], 1);            // rank 0 = heaviest
            int pos = (rank % KCH) * CHST + rank / KCH;   // deal across chunks
            pi[3 * tid + j] = pos;
            inv[pos] = 3 * tid + j;
        }
    }
    __syncthreads();   // inv[] globally written; visible in-block after barrier

    int d0 = 0, d1 = 0, d2 = 0, p0 = 0, p1 = 0, p2 = 0, pg = 0;
    if (tid < 1000) {
        d0 = cnt[inv[3 * tid]]; d1 = cnt[inv[3 * tid + 1]]; d2 = cnt[inv[3 * tid + 2]];
        p0 = (d0 + 3) & ~3; p1 = (d1 + 3) & ~3; p2 = (d2 + 3) & ~3;
        pg = p0 + p1 + p2;
    }
    sc[tid] = pg; __syncthreads();
    for (int o = 1; o < 1024; o <<= 1) {
        int v = (tid >= o) ? sc[tid - o] : 0;
        __syncthreads(); sc[tid] += v; __syncthreads();
    }
    int ex = sc[tid] - pg;
    if (tid < 1000) {
        R[3 * tid] = ex; R[3 * tid + 1] = ex + p0; R[3 * tid + 2] = ex + p0 + p1;
    }
    if (tid == 1000) R[3000] = ex;  // total
}

// 32 blocks x 512: per-graph padded per-state prefix (num)
__global__ void scan_num(const int* __restrict__ cnt, int* __restrict__ R) {
    __shared__ int sc[512];
    int g = blockIdx.x, tid = threadIdx.x;
    int c = 0, pg = 0;
    if (tid < NUM_STATES) { c = cnt[g * NUM_STATES + tid]; pg = (c + 3) & ~3; }
    sc[tid] = pg; __syncthreads();
    for (int o = 1; o < 512; o <<= 1) {
        int v = (tid >= o) ? sc[tid - o] : 0;
        __syncthreads(); sc[tid] += v; __syncthreads();
    }
    int ex = sc[tid] - pg;
    if (tid <= NUM_STATES) R[g * (NUM_STATES + 1) + tid] = ex;
}

// fused scatter (den + num)
__global__ void scat_all(
    const int* __restrict__ dsrc, const int* __restrict__ ddst,
    const int* __restrict__ dlab, const float* __restrict__ dw,
    const int* __restrict__ dR, int* __restrict__ dcur,
    const int* __restrict__ pi, int2* __restrict__ dout,
    const int* __restrict__ nsrc, const int* __restrict__ ndst,
    const int* __restrict__ nlab, const float* __restrict__ nw,
    const int* __restrict__ nR, int* __restrict__ ncur, int2* __restrict__ nout)
{
    int i = blockIdx.x * blockDim.x + threadIdx.x;
    if (i < DEN_ARCS) {
        int dpos = pi[ddst[i]];
        int spos = pi[dsrc[i]];
        int pos = dR[dpos] + atomicAdd(&dcur[dpos], 1);
        dout[pos] = make_int2(spos | (dlab[i] << 16), __float_as_int(__expf(dw[i])));
    }
    if (i < NGRAPH * NUM_ARCS) {
        int g = i / NUM_ARCS;
        int d = ndst[i];
        int pos = nR[g * (NUM_STATES + 1) + d] + atomicAdd(&ncur[g * NUM_STATES + d], 1);
        nout[g * NUM_CAP_G + pos] =
            make_int2(nsrc[i] | (nlab[i] << 16), __float_as_int(__expf(nw[i])));
    }
}

// ---------------------------------------------------------------------------
// num forward: single 768-thread block, prob domain, 1 state/thread
// ---------------------------------------------------------------------------
__device__ __forceinline__ void num_fwd(
    const int* __restrict__ R, const int2* __restrict__ arcs,
    const float* __restrict__ start, const float* __restrict__ fin,
    const float* __restrict__ est, int L, float* __restrict__ out,
    float* A0, float* A1, float* p, float* red)
{
    const int tid = threadIdx.x, lane = tid & 63, wid = tid >> 6;

    if (tid < NUM_STATES) A0[tid] = __expf(start[tid]);

    int rs = 0, re = 0;
    if (tid < NUM_STATES) { rs = R[tid]; re = R[tid + 1]; }

    float l0 = est[tid], l1 = est[tid + 768], l2 = est[tid + 1536];
    float l3 = (tid < 696) ? est[tid + 2304] : 0.f;

    float c = 1.f, OFF = 0.f, pend = 0.f;
    const int4* arcs4 = (const int4*)arcs;

    for (int t = 0; t < L; ++t) {
        OFF += pend;
        p[tid] = __expf(l0) * c;        p[tid + 768] = __expf(l1) * c;
        p[tid + 1536] = __expf(l2) * c;
        if (tid < 696) p[tid + 2304] = __expf(l3) * c;
        {
            const float* nr = est + (size_t)((t + 1 < L) ? (t + 1) : t) * CLASSES;
            l0 = nr[tid]; l1 = nr[tid + 768]; l2 = nr[tid + 1536];
            if (tid < 696) l3 = nr[tid + 2304];
        }
        __syncthreads();   // p ready (also protects red[] from prev iter reads)

        const float* Ac = (t & 1) ? A1 : A0;
        float*       An = (t & 1) ? A0 : A1;
        float a0 = 0.f;
        for (int r = rs; r < re; r += 4) {
            int4 q0 = arcs4[(r >> 1)];
            int4 q1 = arcs4[(r >> 1) + 1];
            a0 += Ac[q0.x & 0xffff] * p[((unsigned)q0.x) >> 16] * __int_as_float(q0.y);
            a0 += Ac[q0.z & 0xffff] * p[((unsigned)q0.z) >> 16] * __int_as_float(q0.w);
            a0 += Ac[q1.x & 0xffff] * p[((unsigned)q1.x) >> 16] * __int_as_float(q1.y);
            a0 += Ac[q1.z & 0xffff] * p[((unsigned)q1.z) >> 16] * __int_as_float(q1.w);
        }
        float mymax = 0.f;
        if (tid < NUM_STATES) { An[tid] = a0; mymax = a0; }
        #pragma unroll
        for (int o = 32; o > 0; o >>= 1) mymax = fmaxf(mymax, __shfl_down(mymax, o, 64));
        if (lane == 0) red[wid] = mymax;
        __syncthreads();
        float M = red[0];
        #pragma unroll
        for (int k = 1; k < NWAVE; ++k) M = fmaxf(M, red[k]);
        M = fmaxf(M, 1e-37f);
        c = 1.0f / M;
        pend = __logf(M);
    }

    const float* Af = (L & 1) ? A1 : A0;
    float fs = 0.f;
    if (tid < NUM_STATES) fs = Af[tid] * __expf(fin[tid]);
    __syncthreads();   // red[] settled
    #pragma unroll
    for (int o = 32; o > 0; o >>= 1) fs += __shfl_down(fs, o, 64);
    if (lane == 0) red[wid] = fs;
    __syncthreads();
    if (tid == 0) {
        float s = 0.f;
        #pragma unroll
        for (int k = 0; k < NWAVE; ++k) s += red[k];
        out[0] = OFF + __logf(s);
    }
}

// ---------------------------------------------------------------------------
// Fused forward: blocks [0,192) = den chunk*32+seq; [192,256) = num.
// Den: KCH=6 chunks exchange alpha per step via LLC with DATA-EMBEDDED TAGS
// (2 mantissa LSBs = (t%3)+1; never 0 = zeroed buffer). One barrier/step,
// double-buffered S1/S2/red; depth-2 software-pipelined arc loop with the
// first 2 iterations' loads issued before the poll. Poll/staging covers all
// 3000 positions by tid-layout (KCH-independent); skew <= 2 steps, so mod-3
// tags disambiguate. Chunks of a seq share the XCD residue (192 = 6*32).
// ---------------------------------------------------------------------------
__global__ __launch_bounds__(BLK) void forward_kernel(
    const float* __restrict__ est, const int* __restrict__ seqlen,
    const int2* __restrict__ den_arcs, const int* __restrict__ den_R,
    const float* __restrict__ den_start, const float* __restrict__ den_final,
    const int* __restrict__ den_inv,
    const int2* __restrict__ num_arcs, const int* __restrict__ num_R,
    const float* __restrict__ num_start, const float* __restrict__ num_final,
    float* __restrict__ galpha,
    float* __restrict__ den_z, float* __restrict__ num_z)
{
    __shared__ float S1[2][DEN_STATES];   // den: alpha (double-buffered) | num: A0/A1
    __shared__ float S2[2][CLASSES];      // den: p (double-buffered)     | num: p
    __shared__ float red[2][16];

    const int blk = blockIdx.x;
    const int tid = threadIdx.x, lane = tid & 63, wid = tid >> 6;

    if (blk < KCH * NSEQ) {
        const int seq = blk & 31;        // chunks of a seq share XCD residue
        const int chunk = blk >> 5;
        const int b = seq & 15;
        const int L = seqlen[b];
        const float* est_base = est + (size_t)seq * TMAX * CLASSES;
        const int base = chunk * CHST;
        unsigned* gaU = (unsigned*)galpha;

        int rs = 0, re = 0;
        if (tid < CHST) { rs = den_R[base + tid]; re = den_R[base + tid + 1]; }
        const int4* arcs4 = (const int4*)den_arcs;
        const int4* ap = arcs4 + (rs >> 1);          // per-thread arc stream base
        const int n4 = (re - rs) >> 2;               // iterations (4 slots each)

        float l0 = est_base[tid], l1 = est_base[tid + 768], l2 = est_base[tid + 1536];
        float l3 = (tid < 696) ? est_base[tid + 2304] : 0.f;

        float OFF = 0.f;

        for (int t = 0; t < L; ++t) {
            const int cur = t & 1;
            float* S1c = S1[cur];
            float* S2c = S2[cur];

            // stage p_raw = exp(llh); prefetch next row (overlaps poll)
            S2c[tid] = __expf(l0); S2c[tid + 768] = __expf(l1); S2c[tid + 1536] = __expf(l2);
            if (tid < 696) S2c[tid + 2304] = __expf(l3);
            {
                const float* nr = est_base + (size_t)((t + 1 < L) ? (t + 1) : t) * CLASSES;
                l0 = nr[tid]; l1 = nr[tid + 768]; l2 = nr[tid + 1536];
                if (tid < 696) l3 = nr[tid + 2304];
            }

            // issue the first two arc-iterations' loads NOW: their L2 latency
            // hides under the poll + barrier
            int4 a0 = ap[0], a1 = ap[1], b0 = ap[2], b1 = ap[3];

            if (t == 0) {
                S1c[tid]        = __expf(den_start[den_inv[tid]]);
                S1c[tid + 768]  = __expf(den_start[den_inv[tid + 768]]);
                S1c[tid + 1536] = __expf(den_start[den_inv[tid + 1536]]);
                if (tid < 696) S1c[tid + 2304] = __expf(den_start[den_inv[tid + 2304]]);
            } else {
                // per-thread data-tag poll on its own 4 gather words
                const unsigned tg = (unsigned)((t - 1) % 3) + 1u;
                const unsigned* gp = gaU + ((size_t)seq * 2 + ((t - 1) & 1)) * DEN_STATES;
                unsigned u0, u1, u2, u3 = tg;   // synthetic match for tid>=696
                for (;;) {
                    u0 = __hip_atomic_load(gp + tid,        __ATOMIC_RELAXED, __HIP_MEMORY_SCOPE_AGENT);
                    u1 = __hip_atomic_load(gp + tid + 768,  __ATOMIC_RELAXED, __HIP_MEMORY_SCOPE_AGENT);
                    u2 = __hip_atomic_load(gp + tid + 1536, __ATOMIC_RELAXED, __HIP_MEMORY_SCOPE_AGENT);
                    if (tid < 696)
                        u3 = __hip_atomic_load(gp + tid + 2304, __ATOMIC_RELAXED, __HIP_MEMORY_SCOPE_AGENT);
                    if ((((u0 & 3u) == tg) && ((u1 & 3u) == tg)) &&
                        (((u2 & 3u) == tg) && ((u3 & 3u) == tg))) break;
                    __builtin_amdgcn_s_sleep(1);
                }
                float x0 = __uint_as_float(u0 & ~3u);
                float x1 = __uint_as_float(u1 & ~3u);
                float x2 = __uint_as_float(u2 & ~3u);
                float x3 = (tid < 696) ? __uint_as_float(u3 & ~3u) : 0.f;
                S1c[tid] = x0; S1c[tid + 768] = x1; S1c[tid + 1536] = x2;
                if (tid < 696) S1c[tid + 2304] = x3;
                // wave-level partial max (block combine deferred past barrier)
                float mymax = fmaxf(fmaxf(x0, x1), fmaxf(x2, x3));
                #pragma unroll
                for (int o = 32; o > 0; o >>= 1)
                    mymax = fmaxf(mymax, __shfl_down(mymax, o, 64));
                if (lane == 0) red[cur][wid] = mymax;
            }

            __syncthreads();   // THE one barrier: S1c,S2c,red[cur] ready

            // combine block max FIRST (3x b128 broadcast reads), so the store
            // can issue immediately after the arc loop's last FMA
            float cM = 1.0f;
            if (t) {
                const float4* r4 = (const float4*)red[cur];
                float4 ra = r4[0], rb = r4[1], rc = r4[2];
                float M = fmaxf(fmaxf(fmaxf(ra.x, ra.y), fmaxf(ra.z, ra.w)),
                         fmaxf(fmaxf(fmaxf(rb.x, rb.y), fmaxf(rb.z, rb.w)),
                               fmaxf(fmaxf(rc.x, rc.y), fmaxf(rc.z, rc.w))));
                M = fmaxf(M, 1e-37f);
                cM = 1.0f / M;
                OFF += __logf(M);
            }

            // depth-2 software-pipelined arc loop
            float acc = 0.f;
            for (int i = 0; i < n4; ++i) {
                int4 p0 = ap[2 * i + 4], p1 = ap[2 * i + 5];   // 2 iters ahead
                acc += S1c[a0.x & 0xffff] * S2c[((unsigned)a0.x) >> 16] * __int_as_float(a0.y);
                acc += S1c[a0.z & 0xffff] * S2c[((unsigned)a0.z) >> 16] * __int_as_float(a0.w);
                acc += S1c[a1.x & 0xffff] * S2c[((unsigned)a1.x) >> 16] * __int_as_float(a1.y);
                acc += S1c[a1.z & 0xffff] * S2c[((unsigned)a1.z) >> 16] * __int_as_float(a1.w);
                a0 = b0; a1 = b1; b0 = p0; b1 = p1;
            }

            if (tid < CHST) {
                unsigned uv = (__float_as_uint(acc * cM) & ~3u) | ((unsigned)(t % 3) + 1u);
                __hip_atomic_store(gaU + ((size_t)seq * 2 + cur) * DEN_STATES + base + tid,
                                   uv, __ATOMIC_RELAXED, __HIP_MEMORY_SCOPE_AGENT);
            }
            asm volatile("" ::: "memory");   // pin the store before next poll
        }

        // epilogue: chunk 0 computes logZ from final buffer (data-tag poll)
        if (chunk == 0) {
            __syncthreads();   // all waves past loop; red free for reuse
            const unsigned tg = (unsigned)((L - 1) % 3) + 1u;
            const unsigned* gp = gaU + ((size_t)seq * 2 + ((L - 1) & 1)) * DEN_STATES;
            unsigned u0, u1, u2, u3 = tg;
            for (;;) {
                u0 = __hip_atomic_load(gp + tid,        __ATOMIC_RELAXED, __HIP_MEMORY_SCOPE_AGENT);
                u1 = __hip_atomic_load(gp + tid + 768,  __ATOMIC_RELAXED, __HIP_MEMORY_SCOPE_AGENT);
                u2 = __hip_atomic_load(gp + tid + 1536, __ATOMIC_RELAXED, __HIP_MEMORY_SCOPE_AGENT);
                if (tid < 696)
                    u3 = __hip_atomic_load(gp + tid + 2304, __ATOMIC_RELAXED, __HIP_MEMORY_SCOPE_AGENT);
                if ((((u0 & 3u) == tg) && ((u1 & 3u) == tg)) &&
                    (((u2 & 3u) == tg) && ((u3 & 3u) == tg))) break;
                __builtin_amdgcn_s_sleep(1);
            }
            float fs = __uint_as_float(u0 & ~3u) * __expf(den_final[den_inv[tid]])
                     + __uint_as_float(u1 & ~3u) * __expf(den_final[den_inv[tid + 768]])
                     + __uint_as_float(u2 & ~3u) * __expf(den_final[den_inv[tid + 1536]]);
            if (tid < 696)
                fs += __uint_as_float(u3 & ~3u) * __expf(den_final[den_inv[tid + 2304]]);
            #pragma unroll
            for (int o = 32; o > 0; o >>= 1) fs += __shfl_down(fs, o, 64);
            if (lane == 0) red[0][wid] = fs;
            __syncthreads();
            if (tid == 0) {
                float s = 0.f;
                #pragma unroll
                for (int k = 0; k < NWAVE; ++k) s += red[0][k];
                den_z[seq] = OFF + __logf(s);
            }
        }
    } else {
        const int q = blk - KCH * NSEQ;
        const int b = q & 15;
        const int sp = q >> 4;
        const int s = sp >> 1, pp = sp & 1;
        const int L = seqlen[b];
        const int g = pp * BATCH + b;
        num_fwd(num_R + (size_t)g * (NUM_STATES + 1),
                num_arcs + (size_t)g * NUM_CAP_G,
                num_start + (size_t)g * NUM_STATES,
                num_final + (size_t)g * NUM_STATES,
                est + (size_t)(s * BATCH + b) * TMAX * CLASSES, L, &num_z[q],
                &S1[0][0], &S1[0][1536], &S2[0][0], &red[0][0]);
    }
}

// ---------------------------------------------------------------------------
__global__ void loss_kernel(const float* __restrict__ den_z,
                            const float* __restrict__ num_z,
                            float* __restrict__ out)
{
    int tid = threadIdx.x;
    float l = 0.f;
    if (tid < BATCH) {
        int b = tid;
        float z00 = num_z[(0 * 2 + 0) * BATCH + b];
        float z01 = num_z[(0 * 2 + 1) * BATCH + b];
        float z10 = num_z[(1 * 2 + 0) * BATCH + b];
        float z11 = num_z[(1 * 2 + 1) * BATCH + b];
        float perm0 = z00 + z11;
        float perm1 = z01 + z10;
        float n0, n1;
        if (perm0 >= perm1) { n0 = z00; n1 = z11; }
        else                { n0 = z01; n1 = z10; }
        l = -(n0 - den_z[0 * BATCH + b]) - (n1 - den_z[1 * BATCH + b]);
    }
    #pragma unroll
    for (int o = 32; o > 0; o >>= 1) l += __shfl_down(l, o, 64);
    if (tid == 0) out[0] = l;
}

// ---------------------------------------------------------------------------
extern "C" void kernel_launch(void* const* d_in, const int* in_sizes, int n_in,
                              void* d_out, int out_size, void* d_ws, size_t ws_size,
                              hipStream_t stream) {
    const float* est        = (const float*)d_in[0];
    const int*   seqlen     = (const int*)d_in[1];
    const int*   num_src    = (const int*)d_in[2];
    const int*   num_dst    = (const int*)d_in[3];
    const int*   num_label  = (const int*)d_in[4];
    const float* num_weight = (const float*)d_in[5];
    const float* num_start  = (const float*)d_in[6];
    const float* num_final  = (const float*)d_in[7];
    const int*   den_src    = (const int*)d_in[8];
    const int*   den_dst    = (const int*)d_in[9];
    const int*   den_label  = (const int*)d_in[10];
    const float* den_weight = (const float*)d_in[11];
    const float* den_start  = (const float*)d_in[12];
    const float* den_final  = (const float*)d_in[13];

    char* ws = (char*)d_ws;
    int2*     den_arcs = (int2*)(ws + WS_DEN_ARCS);
    int2*     num_arcs = (int2*)(ws + WS_NUM_ARCS);
    int*      den_cnt  = (int*)(ws + WS_DEN_CNT);
    int*      den_R    = (int*)(ws + WS_DEN_R);
    int*      den_cur  = (int*)(ws + WS_DEN_CUR);
    int*      num_cnt  = (int*)(ws + WS_NUM_CNT);
    int*      num_R    = (int*)(ws + WS_NUM_R);
    int*      num_cur  = (int*)(ws + WS_NUM_CUR);
    float*    galpha   = (float*)(ws + WS_GALPHA);
    float*    den_z    = (float*)(ws + WS_DEN_Z);
    float*    num_z    = (float*)(ws + WS_NUM_Z);
    int*      pi       = (int*)(ws + WS_PI);
    int*      inv      = (int*)(ws + WS_INV);

    zero_ws<<<512, 256, 0, stream>>>((int*)ws, WS_ZERO_INTS);
    hist_all<<<(DEN_ARCS + 255) / 256, 256, 0, stream>>>(den_dst, den_cnt,
                                                         num_dst, num_cnt);
    prep_den<<<1, 1024, 0, stream>>>(den_cnt, pi, inv, den_R);
    scan_num<<<NGRAPH, 512, 0, stream>>>(num_cnt, num_R);
    scat_all<<<(DEN_ARCS + 255) / 256, 256, 0, stream>>>(
        den_src, den_dst, den_label, den_weight, den_R, den_cur, pi, den_arcs,
        num_src, num_dst, num_label, num_weight, num_R, num_cur, num_arcs);

    forward_kernel<<<KCH * NSEQ + S_SPK * S_SPK * BATCH, BLK, 0, stream>>>(
        est, seqlen, den_arcs, den_R, den_start, den_final, inv,
        num_arcs, num_R, num_start, num_final,
        galpha, den_z, num_z);

    loss_kernel<<<1, 64, 0, stream>>>(den_z, num_z, (float*)d_out);
}